// Round 4
// baseline (386.281 us; speedup 1.0000x reference)
//
#include <hip/hip_runtime.h>
#include <hip/hip_bf16.h>

typedef unsigned short ushort_t;
typedef short short8 __attribute__((ext_vector_type(8)));
typedef short shrt4 __attribute__((ext_vector_type(4)));
typedef unsigned short ush4 __attribute__((ext_vector_type(4)));
typedef unsigned int uintx2 __attribute__((ext_vector_type(2)));
typedef unsigned int uintx4 __attribute__((ext_vector_type(4)));
typedef float floatx4 __attribute__((ext_vector_type(4)));

#define SA 104   // Xin row stride in bf16 elems (h only): 208B = 13*16, 52 dwords % 32 = 20 (conflict-free class)
#define SW 104   // Hhat stride
#define NQ 110592
#define CVOL 32768

// wsW bf16 element offsets
#define L0A   0        // blk0 l0 weights, 16x16x32 A-layout [mt6][kc5][lane][8]
#define L0B   15360    // blk1 l0
#define A1_00 30720    // blk0 l1 weights, 16x16x16 A-layout [mt6][kp3][lane][kl2*4+i]
#define A1_01 39936    // blk0 l2
#define A1_10 49152    // blk1 l1
#define A1_11 58368    // blk1 l2
#define PST   67584    // post weights, 16x16x32 B-layout
#define WTOT  72192
#define BTOT  9216     // bias floats, C-layout [layer6][mt6][lane][r4]

// ws byte offsets
#define WSW_OFF  64
#define BIAS_OFF 147456
#define CVT_OFF  196608

// merged pre-kernel block ranges
#define TXP_NB   256
#define PREP_NB  318
#define PRE_NB   (TXP_NB + PREP_NB + 432)

#if defined(__HIP_DEVICE_COMPILE__)
#define MFMA16(A, B, C) __builtin_amdgcn_mfma_f32_16x16x16bf16_1k(A, B, C, 0, 0, 0)
#else
#define MFMA16(A, B, C) (C)
#endif

#if defined(__HIP_DEVICE_COMPILE__) && __has_builtin(__builtin_amdgcn_sinf) && __has_builtin(__builtin_amdgcn_cosf) && __has_builtin(__builtin_amdgcn_fractf)
#define FAST_SINCOS 1
#else
#define FAST_SINCOS 0
#endif

__device__ __forceinline__ float bf2f(ushort_t u) { return __uint_as_float(((unsigned)u) << 16); }
__device__ __forceinline__ ushort_t f2bf(float f) {         // exact RNE (cold paths)
    unsigned u = __float_as_uint(f);
    unsigned r = (u + 0x7fffu + ((u >> 16) & 1u)) >> 16;
    return (ushort_t)r;
}
// hot-path pack: two f32 -> packed bf16 pair. cvt_pk if HW has it, else
// round-half-up (+0x8000) + v_perm (1.5 ops/elem; differs from RNE only on exact ties).
__device__ __forceinline__ unsigned pkpair(float a, float b) {
#if defined(__HIP_DEVICE_COMPILE__) && __has_builtin(__builtin_amdgcn_cvt_pk_bf16_f32)
    return __builtin_bit_cast(unsigned, __builtin_amdgcn_cvt_pk_bf16_f32(a, b));
#else
    unsigned ua = __float_as_uint(a) + 0x8000u;
    unsigned ub = __float_as_uint(b) + 0x8000u;
    return __builtin_amdgcn_perm(ub, ua, 0x07060302);   // lo16=hi(ua), hi16=hi(ub)
#endif
}
__device__ __forceinline__ shrt4 pk4(floatx4 v) {
    uintx2 u;
    u[0] = pkpair(v[0], v[1]);
    u[1] = pkpair(v[2], v[3]);
    return __builtin_bit_cast(shrt4, u);
}
__device__ __forceinline__ short8 pk8(const float (&v)[8]) {
    uintx4 u;
    u[0] = pkpair(v[0], v[1]);
    u[1] = pkpair(v[2], v[3]);
    u[2] = pkpair(v[4], v[5]);
    u[3] = pkpair(v[6], v[7]);
    return __builtin_bit_cast(short8, u);
}
__device__ __forceinline__ floatx4 silu4(floatx4 z) {
    floatx4 s;
    #pragma unroll
    for (int r = 0; r < 4; ++r)
        s[r] = z[r] * __builtin_amdgcn_rcpf(1.0f + __expf(-z[r]));
    return s;
}
__device__ __forceinline__ unsigned encodeMin(float x) {
    unsigned u = __float_as_uint(x);
    return (u & 0x80000000u) ? ~u : (u | 0x80000000u);
}
__device__ __forceinline__ float decodeMin(unsigned key) {
    unsigned u = (key & 0x80000000u) ? (key ^ 0x80000000u) : ~key;
    return __uint_as_float(u);
}

// revolutions-domain sin/cos (matches reference sin(2*pi*ang))
__device__ __forceinline__ float sin_r(float ang) {
#if FAST_SINCOS
    return __builtin_amdgcn_sinf(__builtin_amdgcn_fractf(ang));
#else
    float s, c; sincospif(2.0f * ang, &s, &c); return s;
#endif
}
__device__ __forceinline__ float cos_r(float ang) {
#if FAST_SINCOS
    return __builtin_amdgcn_cosf(__builtin_amdgcn_fractf(ang));
#else
    float s, c; sincospif(2.0f * ang, &s, &c); return c;
#endif
}

__device__ __constant__ float FREQ[8] = {
    1.0f, 1.2228445f, 1.4953488f, 1.8285791f,
    2.2360680f, 2.7343640f, 3.3437015f, 4.0888269f
};
// compile-time-foldable copy for fully unrolled fragment assembly
constexpr float FREQH[8] = {
    1.0f, 1.2228445f, 1.4953488f, 1.8285791f,
    2.2360680f, 2.7343640f, 3.3437015f, 4.0888269f
};

// ---------------- merged pre-kernel: txp | weight/bias swizzle | min-prepass ----------------
// keys must be pre-initialized to 0xFFFFFFFF (hipMemsetAsync in kernel_launch).
__global__ void decoder_pre(const float* __restrict__ cv, ushort_t* __restrict__ cvT,
                            const float* __restrict__ w00, const float* __restrict__ b00,
                            const float* __restrict__ w01, const float* __restrict__ b01,
                            const float* __restrict__ w02, const float* __restrict__ b02,
                            const float* __restrict__ w10, const float* __restrict__ b10,
                            const float* __restrict__ w11, const float* __restrict__ b11,
                            const float* __restrict__ w12, const float* __restrict__ b12,
                            const float* __restrict__ pw, ushort_t* __restrict__ wsW,
                            float* __restrict__ biasF,
                            const float* __restrict__ qc, const float* __restrict__ ext,
                            unsigned* __restrict__ keys) {
    __shared__ ushort_t ld[128 * SW];
    __shared__ unsigned mk[3];
    const int bx = blockIdx.x;
    const int tid = threadIdx.x;

    if (bx < TXP_NB) {            // ---- transpose cv [96][32768] fp32 -> cvT [32768][96] bf16
        int base = bx * 128;
        int cl = tid & 127, h = tid >> 7;
        #pragma unroll 4
        for (int ch = h * 48; ch < h * 48 + 48; ++ch)
            ld[cl * SW + ch] = f2bf(cv[ch * CVOL + base + cl]);
        __syncthreads();
        #pragma unroll
        for (int it = 0; it < 6; ++it) {
            int idx = it * 256 + tid;
            int r = idx / 12, c = idx - r * 12;
            *(uint4*)&cvT[(base + r) * 96 + c * 8] = *(const uint4*)&ld[r * SW + c * 8];
        }
        return;
    }
    if (bx < TXP_NB + PREP_NB) {  // ---- weight swizzle + bias C-layout
        int idx = (bx - TXP_NB) * 256 + tid;
        if (idx >= WTOT + BTOT) return;
        if (idx >= WTOT) {
            int t = idx - WTOT;
            int layer = t / 1536, rem = t - layer * 1536;
            int mt = rem >> 8, l2i = rem & 255;
            int lane = l2i >> 2, r = l2i & 3;
            int m = mt * 16 + (lane >> 4) * 4 + r;
            const float* B = layer == 0 ? b00 : layer == 1 ? b01 : layer == 2 ? b02
                           : layer == 3 ? b10 : layer == 4 ? b11 : b12;
            biasF[t] = B[m];
            return;
        }
        ushort_t v = 0;
        if (idx < A1_00) {            // layer-0 weights: 16x16x32 A-layout
            const float* W = (idx < L0B) ? w00 : w10;
            int li = idx - ((idx < L0B) ? L0A : L0B);
            int j = li & 7, lane = (li >> 3) & 63, chunk = li >> 9;
            int kc = chunk % 5, mt = chunk / 5;
            int k = kc * 32 + (lane >> 4) * 8 + j;
            int m = mt * 16 + (lane & 15);
            if (k < 156) v = f2bf(W[k * 96 + m]);
        } else if (idx < PST) {       // layer-1/2 weights: 16x16x16 A-layout
            const float* W = idx < A1_01 ? w01 : idx < A1_10 ? w02 : idx < A1_11 ? w11 : w12;
            int off = idx < A1_01 ? A1_00 : idx < A1_10 ? A1_01 : idx < A1_11 ? A1_10 : A1_11;
            int li = idx - off;
            int i = li & 3, kl = (li >> 2) & 1, lane = (li >> 3) & 63, chunk = li >> 9;
            int kp = chunk % 3, mt = chunk / 3;
            int k = (kp * 2 + kl) * 16 + (lane >> 4) * 4 + i;
            int m = mt * 16 + (lane & 15);
            v = f2bf(W[k * 96 + m]);
        } else {                      // post weights: 16x16x32 B-layout
            int li = idx - PST;
            int j = li & 7, lane = (li >> 3) & 63, chunk = li >> 9;
            int kc = chunk % 3, t = chunk / 3;
            int k = kc * 32 + (lane >> 4) * 8 + j;
            int n = t * 16 + (lane & 15);
            if (n < 45) v = f2bf(pw[k * 45 + n]);
        }
        wsW[idx] = v;
        return;
    }
    // ---- prepass: global min of base_c = org + ci*vox - q
    {
        int lane = tid & 63;
        if (tid < 3) mk[tid] = 0xFFFFFFFFu;
        __syncthreads();
        int p = (bx - TXP_NB - PREP_NB) * 256 + tid;
        #pragma unroll
        for (int c = 0; c < 3; ++c) {
            float org = ext[c * CVOL];
            float vox = fabsf(ext[c * CVOL + 1057] - org);
            float q = qc[c * NQ + p];
            float nf = rintf((q - org) / vox);
            int ci = (int)nf; ci = ci < 0 ? 0 : (ci > 30 ? 30 : ci);
            float base = org + (float)ci * vox - q;
            for (int off = 32; off > 0; off >>= 1) base = fminf(base, __shfl_xor(base, off));
            if (lane == 0) atomicMin(&mk[c], encodeMin(base));
        }
        __syncthreads();
        if (tid < 3) atomicMin(&keys[tid], mk[tid]);
    }
}

// ---------------- main fused kernel ----------------
// __launch_bounds__(256, 3): the only harness-verified no-scratch attribute
// config (rounds 1-2: 4-wave hints -> 64-VGPR squeeze + ~140 MB scratch).
// Round-3 lesson: even spill-free, the allocator stays at 64 arch VGPRs and
// round-trips excess live state through AGPRs (VALU cost). This version makes
// nt the OUTER MLP loop so persistent fragments halve (bA[6]/bB[6] instead of
// [6][2]) and peak live state fits the 64-VGPR budget without AGPR churn.
__global__ __launch_bounds__(256, 3) void decoder_main(
    const ushort_t* __restrict__ cvT, const float* __restrict__ ext,
    const float* __restrict__ qvx, const float* __restrict__ qc,
    const float* __restrict__ pb, const ushort_t* __restrict__ wsW,
    const float* __restrict__ biasF,
    const unsigned* __restrict__ minKeys, float* __restrict__ out)
{
    __shared__ ushort_t Xin[128 * SA];     // rows = batch (point,corner), cols = h(96) + 8 pad
    __shared__ ushort_t Hhat[16 * SW];
    __shared__ float ptQ[3][16], ptBase[3][16], ptT[3][16];
    __shared__ int ptCI[3][16];
    __shared__ float wcorn[16][8];

    const int tid = threadIdx.x;
    const int lane = tid & 63;
    const int wv = tid >> 6;
    const int quad = lane >> 4;
    const int l16 = lane & 15;
    const int lane8 = lane << 3, quad8 = quad * 8, quad4 = quad * 4;
    const int p0 = blockIdx.x * 16;
    const int col0 = wv * 32;              // wave-private batch columns [col0, col0+32)

    // broadcast scalars
    float vox[3], org[3], lim[3], inv3v[3], qv[3], mrel[3][2];
    #pragma unroll
    for (int c = 0; c < 3; ++c) {
        org[c] = ext[c * CVOL];
        vox[c] = fabsf(ext[c * CVOL + 1057] - org[c]);
        lim[c] = -0.5f * vox[c] + 1e-7f;
        inv3v[c] = 1.0f / (1.5f * vox[c]);
        qv[c] = qvx[c];
        float mb = decodeMin(minKeys[c]);
        mrel[c][0] = fmaxf(mb, lim[c]);
        mrel[c][1] = fmaxf(mb + vox[c], lim[c]);
    }

    // per-point setup
    if (tid < 64) {
        int p = tid >> 2, c = tid & 3;
        if (c < 3) {
            float q = qc[c * NQ + p0 + p];
            float nf = rintf((q - org[c]) / vox[c]);   // RNE == jnp.round
            int ci = (int)nf; ci = ci < 0 ? 0 : (ci > 30 ? 30 : ci);
            float base = org[c] + (float)ci * vox[c] - q;
            float rel0 = fmaxf(base, lim[c]);
            float g = fminf(fmaxf((rel0 - 0.5f) * 2.0f, -1.0f + 1e-7f), 1.0f - 1e-7f);
            ptQ[c][p] = q; ptCI[c][p] = ci; ptBase[c][p] = base; ptT[c][p] = (g + 1.0f) * 0.5f;
        }
    }
    __syncthreads();

    // trilinear corner weights (reference's channel swap: i->t[2], j->t[1], k->t[0])
    if (tid < 128) {
        int p = tid >> 3, corner = tid & 7;
        int i = corner >> 2, j = (corner >> 1) & 1, k = corner & 1;
        float wx = i ? ptT[2][p] : 1.0f - ptT[2][p];
        float wy = j ? ptT[1][p] : 1.0f - ptT[1][p];
        float wz = k ? ptT[0][p] : 1.0f - ptT[0][p];
        wcorn[p][corner] = wx * wy * wz;
    }

    // gather h (coalesced bf16 cvT) into wave-private Xin; 2 threads per batch row
    {
        const int r = tid >> 1, h = tid & 1;
        const int p = r >> 3, corner = r & 7;
        const int i0 = corner >> 2, i1 = (corner >> 1) & 1, i2 = corner & 1;
        int cell = (ptCI[0][p] + i0) * 1024 + (ptCI[1][p] + i1) * 32 + ptCI[2][p] + i2;
        const uint4* src = (const uint4*)&cvT[cell * 96];
        uint4* dstX = (uint4*)&Xin[r * SA];
        #pragma unroll
        for (int cc = h * 6; cc < h * 6 + 6; ++cc) dstX[cc] = src[cc];
    }

    // coord-feature B-fragments (kc=3,4 of layer-0) computed straight into
    // registers in MFMA B-layout: lane l16 = row col0+nt*16+l16, elem (quad,j)
    // covers feature index f = (kc-3)*32 + quad*8 + j. Each sin/cos of the
    // block is computed exactly once (quad-partitioned), no LDS staging.
    short8 bF3[2], bF4[2];
    #pragma unroll
    for (int nt = 0; nt < 2; ++nt) {
        const int r = col0 + nt * 16 + l16;
        const int p = r >> 3, corner = r & 7;
        const int io[3] = {corner >> 2, (corner >> 1) & 1, corner & 1};
        float rn[3], cc3[3], qp[3];
        #pragma unroll
        for (int c = 0; c < 3; ++c) {
            float rel = fmaxf(ptBase[c][p] + (float)io[c] * vox[c], lim[c]);
            rn[c] = (rel - mrel[c][io[c]]) * inv3v[c];
            cc3[c] = org[c] + (float)(ptCI[c][p] + io[c]) * vox[c];
            qp[c] = ptQ[c][p];
        }
        float fa[8], fb[8];
        if (quad == 0) {
            fa[0] = qv[0]; fa[1] = qv[1]; fa[2] = qv[2];
            fa[3] = cc3[0]; fa[4] = cc3[1]; fa[5] = cc3[2];
            fa[6] = qp[0]; fa[7] = qp[1];
            #pragma unroll
            for (int m = 0; m < 4; ++m) fb[m]     = sin_r(rn[1] * FREQH[4 + m]);
            #pragma unroll
            for (int m = 0; m < 4; ++m) fb[4 + m] = cos_r(rn[1] * FREQH[m]);
        } else if (quad == 1) {
            fa[0] = qp[2]; fa[1] = rn[0]; fa[2] = rn[1]; fa[3] = rn[2];
            #pragma unroll
            for (int m = 0; m < 4; ++m) fa[4 + m] = sin_r(rn[0] * FREQH[m]);
            #pragma unroll
            for (int m = 0; m < 4; ++m) fb[m]     = cos_r(rn[1] * FREQH[4 + m]);
            #pragma unroll
            for (int m = 0; m < 4; ++m) fb[4 + m] = sin_r(rn[2] * FREQH[m]);
        } else if (quad == 2) {
            #pragma unroll
            for (int m = 0; m < 4; ++m) fa[m]     = sin_r(rn[0] * FREQH[4 + m]);
            #pragma unroll
            for (int m = 0; m < 4; ++m) fa[4 + m] = cos_r(rn[0] * FREQH[m]);
            #pragma unroll
            for (int m = 0; m < 4; ++m) fb[m]     = sin_r(rn[2] * FREQH[4 + m]);
            #pragma unroll
            for (int m = 0; m < 4; ++m) fb[4 + m] = cos_r(rn[2] * FREQH[m]);
        } else {
            #pragma unroll
            for (int m = 0; m < 4; ++m) fa[m]     = cos_r(rn[0] * FREQH[4 + m]);
            #pragma unroll
            for (int m = 0; m < 4; ++m) fa[4 + m] = sin_r(rn[1] * FREQH[m]);
            #pragma unroll
            for (int m = 0; m < 4; ++m) fb[m]     = cos_r(rn[2] * FREQH[4 + m]);
            fb[4] = 0.f; fb[5] = 0.f; fb[6] = 0.f; fb[7] = 0.f;   // k=156..159 (weights also zeroed)
        }
        bF3[nt] = pk8(fa);
        bF4[nt] = pk8(fb);
    }
    __syncthreads();

    const int A32off[2] = {L0A, L0B};
    const int A16off[2][2] = {{A1_00, A1_01}, {A1_10, A1_11}};
    // nt-outer MLP chain: only bA[6]/bB[6] (12 VGPRs each) persist at any
    // point; bA dead after layer 1, bB dead after layer 2. Weights/bias are
    // re-fetched per nt (L2-resident, VMEM issue only) -- trades cheap VMEM
    // for VALU-visible register churn.
    shrt4 bA[6], bB[6];

    #pragma unroll
    for (int blk = 0; blk < 2; ++blk) {
        #pragma unroll
        for (int nt = 0; nt < 2; ++nt) {
            const int rowb = (col0 + nt * 16 + l16) * SA;
            // ---- layer 0: K=160, mfma 16x16x32; bias rides in as C; silu fused -> bA
            {
                const short8 bX0 = *(const short8*)&Xin[rowb + 0 * 32 + quad8];
                const short8 bX1 = *(const short8*)&Xin[rowb + 1 * 32 + quad8];
                const short8 bX2 = *(const short8*)&Xin[rowb + 2 * 32 + quad8];
                const int lay = blk * 3;
                #pragma unroll
                for (int mt = 0; mt < 6; ++mt) {
                    short8 aw[5];
                    #pragma unroll
                    for (int kc = 0; kc < 5; ++kc)
                        aw[kc] = *(const short8*)&wsW[A32off[blk] + ((mt * 5 + kc) << 9) + lane8];
                    floatx4 bv = *(const floatx4*)&biasF[((lay * 6 + mt) << 8) + (lane << 2)];
                    floatx4 a = __builtin_amdgcn_mfma_f32_16x16x32_bf16(aw[0], bX0, bv, 0, 0, 0);
                    a = __builtin_amdgcn_mfma_f32_16x16x32_bf16(aw[1], bX1, a, 0, 0, 0);
                    a = __builtin_amdgcn_mfma_f32_16x16x32_bf16(aw[2], bX2, a, 0, 0, 0);
                    a = __builtin_amdgcn_mfma_f32_16x16x32_bf16(aw[3], bF3[nt], a, 0, 0, 0);
                    a = __builtin_amdgcn_mfma_f32_16x16x32_bf16(aw[4], bF4[nt], a, 0, 0, 0);
                    bA[mt] = pk4(silu4(a));
                }
            }
            // ---- layer 1: K=96, mfma 16x16x16 chained from bA; silu fused -> bB
            {
                const int lay = blk * 3 + 1;
                #pragma unroll
                for (int mt = 0; mt < 6; ++mt) {
                    short8 awp[3];
                    #pragma unroll
                    for (int kp = 0; kp < 3; ++kp)
                        awp[kp] = *(const short8*)&wsW[A16off[blk][0] + ((mt * 3 + kp) << 9) + lane8];
                    floatx4 bv = *(const floatx4*)&biasF[((lay * 6 + mt) << 8) + (lane << 2)];
                    shrt4 a0 = __builtin_shufflevector(awp[0], awp[0], 0, 1, 2, 3);
                    floatx4 a = MFMA16(a0, bA[0], bv);
                    #pragma unroll
                    for (int kc = 1; kc < 6; ++kc) {
                        shrt4 af = (kc & 1)
                            ? __builtin_shufflevector(awp[kc >> 1], awp[kc >> 1], 4, 5, 6, 7)
                            : __builtin_shufflevector(awp[kc >> 1], awp[kc >> 1], 0, 1, 2, 3);
                        a = MFMA16(af, bA[kc], a);
                    }
                    bB[mt] = pk4(silu4(a));
                }
            }
            // ---- layer 2: K=96 from bB; silu + residual + h write-back fused (wave-private Xin)
            {
                const int lay = blk * 3 + 2;
                #pragma unroll
                for (int mt = 0; mt < 6; ++mt) {
                    short8 awp[3];
                    #pragma unroll
                    for (int kp = 0; kp < 3; ++kp)
                        awp[kp] = *(const short8*)&wsW[A16off[blk][1] + ((mt * 3 + kp) << 9) + lane8];
                    floatx4 bv = *(const floatx4*)&biasF[((lay * 6 + mt) << 8) + (lane << 2)];
                    shrt4 a0 = __builtin_shufflevector(awp[0], awp[0], 0, 1, 2, 3);
                    floatx4 a = MFMA16(a0, bB[0], bv);
                    #pragma unroll
                    for (int kc = 1; kc < 6; ++kc) {
                        shrt4 af = (kc & 1)
                            ? __builtin_shufflevector(awp[kc >> 1], awp[kc >> 1], 4, 5, 6, 7)
                            : __builtin_shufflevector(awp[kc >> 1], awp[kc >> 1], 0, 1, 2, 3);
                        a = MFMA16(af, bB[kc], a);
                    }
                    int ca = rowb + mt * 16 + quad4;
                    ush4 hu = *(const ush4*)&Xin[ca];      // residual source
                    floatx4 s;
                    #pragma unroll
                    for (int r = 0; r < 4; ++r)
                        s[r] = a[r] * __builtin_amdgcn_rcpf(1.0f + __expf(-a[r])) + bf2f(hu[r]);
                    uintx2 w;
                    w[0] = pkpair(s[0], s[1]);
                    w[1] = pkpair(s[2], s[3]);
                    *(uintx2*)&Xin[ca] = w;                // same-wave readers only
                }
            }
        }
    }

    // blend 8 corners -> Hhat (wave-private), b32 reads + hi/lo unpack
    {
        int p = tid >> 4, s6 = (tid & 15) * 6;
        float w8[8];
        #pragma unroll
        for (int c = 0; c < 8; ++c) w8[c] = wcorn[p][c];
        float sum[6] = {0.f, 0.f, 0.f, 0.f, 0.f, 0.f};
        #pragma unroll
        for (int c = 0; c < 8; ++c) {
            const unsigned* rp = (const unsigned*)&Xin[(p * 8 + c) * SA + s6];
            float w = w8[c];
            #pragma unroll
            for (int d = 0; d < 3; ++d) {
                unsigned u = rp[d];
                sum[d * 2]     += w * __uint_as_float(u << 16);
                sum[d * 2 + 1] += w * __uint_as_float(u & 0xFFFF0000u);
            }
        }
        unsigned* hp = (unsigned*)&Hhat[p * SW + s6];
        #pragma unroll
        for (int d = 0; d < 3; ++d) hp[d] = pkpair(sum[d * 2], sum[d * 2 + 1]);
    }
    __syncthreads();   // Hhat is read cross-wave by the post GEMM

    // post GEMM: 16 points x 48(45) out channels
    if (wv < 3) {
        const ushort_t* wb = wsW + PST;
        floatx4 pacc = {0.f, 0.f, 0.f, 0.f};
        #pragma unroll
        for (int kc = 0; kc < 3; ++kc) {
            short8 a = *(const short8*)&Hhat[l16 * SW + kc * 32 + quad8];
            short8 bfrag = *(const short8*)&wb[((wv * 3 + kc) << 9) + lane8];
            pacc = __builtin_amdgcn_mfma_f32_16x16x32_bf16(a, bfrag, pacc, 0, 0, 0);
        }
        int n = 16 * wv + l16;
        if (n < 45) {
            float bv = pb[n];
            float4 v;
            v.x = pacc[0] + bv; v.y = pacc[1] + bv; v.z = pacc[2] + bv; v.w = pacc[3] + bv;
            *(float4*)&out[n * NQ + p0 + quad * 4] = v;
        }
    }
}

extern "C" void kernel_launch(void* const* d_in, const int* in_sizes, int n_in,
                              void* d_out, int out_size, void* d_ws, size_t ws_size,
                              hipStream_t stream) {
    (void)in_sizes; (void)n_in; (void)out_size; (void)ws_size;
    const float* cv  = (const float*)d_in[0];
    const float* ext = (const float*)d_in[1];
    const float* qvx = (const float*)d_in[2];
    const float* qc  = (const float*)d_in[3];
    const float* w00 = (const float*)d_in[4];
    const float* b00 = (const float*)d_in[5];
    const float* w01 = (const float*)d_in[6];
    const float* b01 = (const float*)d_in[7];
    const float* w02 = (const float*)d_in[8];
    const float* b02 = (const float*)d_in[9];
    const float* w10 = (const float*)d_in[10];
    const float* b10 = (const float*)d_in[11];
    const float* w11 = (const float*)d_in[12];
    const float* b11 = (const float*)d_in[13];
    const float* w12 = (const float*)d_in[14];
    const float* b12 = (const float*)d_in[15];
    const float* pw  = (const float*)d_in[16];
    const float* pb  = (const float*)d_in[17];

    unsigned* keys = (unsigned*)d_ws;
    ushort_t* wsW  = (ushort_t*)((char*)d_ws + WSW_OFF);
    float* biasF   = (float*)((char*)d_ws + BIAS_OFF);
    ushort_t* cvT  = (ushort_t*)((char*)d_ws + CVT_OFF);

    hipMemsetAsync(keys, 0xFF, 12, stream);   // atomicMin identity (graph-safe)
    decoder_pre<<<PRE_NB, 256, 0, stream>>>(cv, cvT,
                                            w00, b00, w01, b01, w02, b02,
                                            w10, b10, w11, b11, w12, b12,
                                            pw, wsW, biasF, qc, ext, keys);
    decoder_main<<<6912, 256, 0, stream>>>(cvT, ext, qvx, qc,
                                           pb, wsW, biasF, keys, (float*)d_out);
}

// Round 5
// 322.231 us; speedup vs baseline: 1.1988x; 1.1988x over previous
//
#include <hip/hip_runtime.h>
#include <hip/hip_bf16.h>

typedef unsigned short ushort_t;
typedef short short8 __attribute__((ext_vector_type(8)));
typedef short shrt4 __attribute__((ext_vector_type(4)));
typedef unsigned short ush4 __attribute__((ext_vector_type(4)));
typedef unsigned int uintx2 __attribute__((ext_vector_type(2)));
typedef unsigned int uintx4 __attribute__((ext_vector_type(4)));
typedef float floatx4 __attribute__((ext_vector_type(4)));

#define SA 104   // Xin row stride in bf16 elems (h only): 208B = 13*16, 52 dwords % 32 = 20 (conflict-free class)
#define SW 104   // Hhat stride
#define NQ 110592
#define CVOL 32768

// wsW bf16 element offsets
#define L0A   0        // blk0 l0 weights, 16x16x32 A-layout [mt6][kc5][lane][8]
#define L0B   15360    // blk1 l0
#define A1_00 30720    // blk0 l1 weights, 16x16x16 A-layout [mt6][kp3][lane][kl2*4+i]
#define A1_01 39936    // blk0 l2
#define A1_10 49152    // blk1 l1
#define A1_11 58368    // blk1 l2
#define PST   67584    // post weights, 16x16x32 B-layout
#define WTOT  72192
#define BTOT  9216     // bias floats, C-layout [layer6][mt6][lane][r4]

// ws byte offsets
#define WSW_OFF  64
#define BIAS_OFF 147456
#define CVT_OFF  196608

// merged pre-kernel block ranges
#define TXP_NB   256
#define PREP_NB  318
#define PRE_NB   (TXP_NB + PREP_NB + 432)

#if defined(__HIP_DEVICE_COMPILE__)
#define MFMA16(A, B, C) __builtin_amdgcn_mfma_f32_16x16x16bf16_1k(A, B, C, 0, 0, 0)
#else
#define MFMA16(A, B, C) (C)
#endif

#if defined(__HIP_DEVICE_COMPILE__) && __has_builtin(__builtin_amdgcn_sinf) && __has_builtin(__builtin_amdgcn_cosf) && __has_builtin(__builtin_amdgcn_fractf)
#define FAST_SINCOS 1
#else
#define FAST_SINCOS 0
#endif

__device__ __forceinline__ float bf2f(ushort_t u) { return __uint_as_float(((unsigned)u) << 16); }
__device__ __forceinline__ ushort_t f2bf(float f) {         // exact RNE (cold paths)
    unsigned u = __float_as_uint(f);
    unsigned r = (u + 0x7fffu + ((u >> 16) & 1u)) >> 16;
    return (ushort_t)r;
}
// hot-path pack: two f32 -> packed bf16 pair. cvt_pk if HW has it, else
// round-half-up (+0x8000) + v_perm (1.5 ops/elem; differs from RNE only on exact ties).
__device__ __forceinline__ unsigned pkpair(float a, float b) {
#if defined(__HIP_DEVICE_COMPILE__) && __has_builtin(__builtin_amdgcn_cvt_pk_bf16_f32)
    return __builtin_bit_cast(unsigned, __builtin_amdgcn_cvt_pk_bf16_f32(a, b));
#else
    unsigned ua = __float_as_uint(a) + 0x8000u;
    unsigned ub = __float_as_uint(b) + 0x8000u;
    return __builtin_amdgcn_perm(ub, ua, 0x07060302);   // lo16=hi(ua), hi16=hi(ub)
#endif
}
__device__ __forceinline__ shrt4 pk4(floatx4 v) {
    uintx2 u;
    u[0] = pkpair(v[0], v[1]);
    u[1] = pkpair(v[2], v[3]);
    return __builtin_bit_cast(shrt4, u);
}
__device__ __forceinline__ short8 pk8(const float (&v)[8]) {
    uintx4 u;
    u[0] = pkpair(v[0], v[1]);
    u[1] = pkpair(v[2], v[3]);
    u[2] = pkpair(v[4], v[5]);
    u[3] = pkpair(v[6], v[7]);
    return __builtin_bit_cast(short8, u);
}
__device__ __forceinline__ floatx4 silu4(floatx4 z) {
    floatx4 s;
    #pragma unroll
    for (int r = 0; r < 4; ++r)
        s[r] = z[r] * __builtin_amdgcn_rcpf(1.0f + __expf(-z[r]));
    return s;
}
__device__ __forceinline__ unsigned encodeMin(float x) {
    unsigned u = __float_as_uint(x);
    return (u & 0x80000000u) ? ~u : (u | 0x80000000u);
}
__device__ __forceinline__ float decodeMin(unsigned key) {
    unsigned u = (key & 0x80000000u) ? (key ^ 0x80000000u) : ~key;
    return __uint_as_float(u);
}

// revolutions-domain sin/cos (matches reference sin(2*pi*ang))
__device__ __forceinline__ float sin_r(float ang) {
#if FAST_SINCOS
    return __builtin_amdgcn_sinf(__builtin_amdgcn_fractf(ang));
#else
    float s, c; sincospif(2.0f * ang, &s, &c); return s;
#endif
}
__device__ __forceinline__ float cos_r(float ang) {
#if FAST_SINCOS
    return __builtin_amdgcn_cosf(__builtin_amdgcn_fractf(ang));
#else
    float s, c; sincospif(2.0f * ang, &s, &c); return c;
#endif
}

__device__ __constant__ float FREQ[8] = {
    1.0f, 1.2228445f, 1.4953488f, 1.8285791f,
    2.2360680f, 2.7343640f, 3.3437015f, 4.0888269f
};
// compile-time-foldable copy for fully unrolled fragment assembly
constexpr float FREQH[8] = {
    1.0f, 1.2228445f, 1.4953488f, 1.8285791f,
    2.2360680f, 2.7343640f, 3.3437015f, 4.0888269f
};

// ---------------- merged pre-kernel: txp | weight/bias swizzle | min-prepass ----------------
// keys must be pre-initialized to 0xFFFFFFFF (hipMemsetAsync in kernel_launch).
__global__ void decoder_pre(const float* __restrict__ cv, ushort_t* __restrict__ cvT,
                            const float* __restrict__ w00, const float* __restrict__ b00,
                            const float* __restrict__ w01, const float* __restrict__ b01,
                            const float* __restrict__ w02, const float* __restrict__ b02,
                            const float* __restrict__ w10, const float* __restrict__ b10,
                            const float* __restrict__ w11, const float* __restrict__ b11,
                            const float* __restrict__ w12, const float* __restrict__ b12,
                            const float* __restrict__ pw, ushort_t* __restrict__ wsW,
                            float* __restrict__ biasF,
                            const float* __restrict__ qc, const float* __restrict__ ext,
                            unsigned* __restrict__ keys) {
    __shared__ ushort_t ld[128 * SW];
    __shared__ unsigned mk[3];
    const int bx = blockIdx.x;
    const int tid = threadIdx.x;

    if (bx < TXP_NB) {            // ---- transpose cv [96][32768] fp32 -> cvT [32768][96] bf16
        int base = bx * 128;
        int cl = tid & 127, h = tid >> 7;
        #pragma unroll 4
        for (int ch = h * 48; ch < h * 48 + 48; ++ch)
            ld[cl * SW + ch] = f2bf(cv[ch * CVOL + base + cl]);
        __syncthreads();
        #pragma unroll
        for (int it = 0; it < 6; ++it) {
            int idx = it * 256 + tid;
            int r = idx / 12, c = idx - r * 12;
            *(uint4*)&cvT[(base + r) * 96 + c * 8] = *(const uint4*)&ld[r * SW + c * 8];
        }
        return;
    }
    if (bx < TXP_NB + PREP_NB) {  // ---- weight swizzle + bias C-layout
        int idx = (bx - TXP_NB) * 256 + tid;
        if (idx >= WTOT + BTOT) return;
        if (idx >= WTOT) {
            int t = idx - WTOT;
            int layer = t / 1536, rem = t - layer * 1536;
            int mt = rem >> 8, l2i = rem & 255;
            int lane = l2i >> 2, r = l2i & 3;
            int m = mt * 16 + (lane >> 4) * 4 + r;
            const float* B = layer == 0 ? b00 : layer == 1 ? b01 : layer == 2 ? b02
                           : layer == 3 ? b10 : layer == 4 ? b11 : b12;
            biasF[t] = B[m];
            return;
        }
        ushort_t v = 0;
        if (idx < A1_00) {            // layer-0 weights: 16x16x32 A-layout
            const float* W = (idx < L0B) ? w00 : w10;
            int li = idx - ((idx < L0B) ? L0A : L0B);
            int j = li & 7, lane = (li >> 3) & 63, chunk = li >> 9;
            int kc = chunk % 5, mt = chunk / 5;
            int k = kc * 32 + (lane >> 4) * 8 + j;
            int m = mt * 16 + (lane & 15);
            if (k < 156) v = f2bf(W[k * 96 + m]);
        } else if (idx < PST) {       // layer-1/2 weights: 16x16x16 A-layout
            const float* W = idx < A1_01 ? w01 : idx < A1_10 ? w02 : idx < A1_11 ? w11 : w12;
            int off = idx < A1_01 ? A1_00 : idx < A1_10 ? A1_01 : idx < A1_11 ? A1_10 : A1_11;
            int li = idx - off;
            int i = li & 3, kl = (li >> 2) & 1, lane = (li >> 3) & 63, chunk = li >> 9;
            int kp = chunk % 3, mt = chunk / 3;
            int k = (kp * 2 + kl) * 16 + (lane >> 4) * 4 + i;
            int m = mt * 16 + (lane & 15);
            v = f2bf(W[k * 96 + m]);
        } else {                      // post weights: 16x16x32 B-layout
            int li = idx - PST;
            int j = li & 7, lane = (li >> 3) & 63, chunk = li >> 9;
            int kc = chunk % 3, t = chunk / 3;
            int k = kc * 32 + (lane >> 4) * 8 + j;
            int n = t * 16 + (lane & 15);
            if (n < 45) v = f2bf(pw[k * 45 + n]);
        }
        wsW[idx] = v;
        return;
    }
    // ---- prepass: global min of base_c = org + ci*vox - q
    {
        int lane = tid & 63;
        if (tid < 3) mk[tid] = 0xFFFFFFFFu;
        __syncthreads();
        int p = (bx - TXP_NB - PREP_NB) * 256 + tid;
        #pragma unroll
        for (int c = 0; c < 3; ++c) {
            float org = ext[c * CVOL];
            float vox = fabsf(ext[c * CVOL + 1057] - org);
            float q = qc[c * NQ + p];
            float nf = rintf((q - org) / vox);
            int ci = (int)nf; ci = ci < 0 ? 0 : (ci > 30 ? 30 : ci);
            float base = org + (float)ci * vox - q;
            for (int off = 32; off > 0; off >>= 1) base = fminf(base, __shfl_xor(base, off));
            if (lane == 0) atomicMin(&mk[c], encodeMin(base));
        }
        __syncthreads();
        if (tid < 3) atomicMin(&keys[tid], mk[tid]);
    }
}

// ---------------- main fused kernel ----------------
// Structure = round-3 best (nt-INNER MLP: two independent MFMA chains per mt
// give the ILP that hides the serial accumulator chain + silu trans latency;
// round 4's nt-outer variant lost 36% to latency stalls).
// Attribute probe: __launch_bounds__(256, 2) -> 256-VGPR budget. Round-3 ran
// at a self-imposed 64-arch-VGPR ceiling with heavy operand/AGPR copy churn
// (VALUBusy 80% vs ~40% algorithmic need). LDS 31.2 KB still allows 5
// blocks/CU; <=102 VGPR keeps that, <=128 gives 4.
__global__ __launch_bounds__(256, 2) void decoder_main(
    const ushort_t* __restrict__ cvT, const float* __restrict__ ext,
    const float* __restrict__ qvx, const float* __restrict__ qc,
    const float* __restrict__ pb, const ushort_t* __restrict__ wsW,
    const float* __restrict__ biasF,
    const unsigned* __restrict__ minKeys, float* __restrict__ out)
{
    __shared__ ushort_t Xin[128 * SA];     // rows = batch (point,corner), cols = h(96) + 8 pad
    __shared__ ushort_t Hhat[16 * SW];
    __shared__ float ptQ[3][16], ptBase[3][16], ptT[3][16];
    __shared__ int ptCI[3][16];
    __shared__ float wcorn[16][8];

    const int tid = threadIdx.x;
    const int lane = tid & 63;
    const int wv = tid >> 6;
    const int quad = lane >> 4;
    const int l16 = lane & 15;
    const int lane8 = lane << 3, quad8 = quad * 8, quad4 = quad * 4;
    const int p0 = blockIdx.x * 16;
    const int col0 = wv * 32;              // wave-private batch columns [col0, col0+32)

    // broadcast scalars
    float vox[3], org[3], lim[3], inv3v[3], qv[3], mrel[3][2];
    #pragma unroll
    for (int c = 0; c < 3; ++c) {
        org[c] = ext[c * CVOL];
        vox[c] = fabsf(ext[c * CVOL + 1057] - org[c]);
        lim[c] = -0.5f * vox[c] + 1e-7f;
        inv3v[c] = 1.0f / (1.5f * vox[c]);
        qv[c] = qvx[c];
        float mb = decodeMin(minKeys[c]);
        mrel[c][0] = fmaxf(mb, lim[c]);
        mrel[c][1] = fmaxf(mb + vox[c], lim[c]);
    }

    // per-point setup
    if (tid < 64) {
        int p = tid >> 2, c = tid & 3;
        if (c < 3) {
            float q = qc[c * NQ + p0 + p];
            float nf = rintf((q - org[c]) / vox[c]);   // RNE == jnp.round
            int ci = (int)nf; ci = ci < 0 ? 0 : (ci > 30 ? 30 : ci);
            float base = org[c] + (float)ci * vox[c] - q;
            float rel0 = fmaxf(base, lim[c]);
            float g = fminf(fmaxf((rel0 - 0.5f) * 2.0f, -1.0f + 1e-7f), 1.0f - 1e-7f);
            ptQ[c][p] = q; ptCI[c][p] = ci; ptBase[c][p] = base; ptT[c][p] = (g + 1.0f) * 0.5f;
        }
    }
    __syncthreads();

    // trilinear corner weights (reference's channel swap: i->t[2], j->t[1], k->t[0])
    if (tid < 128) {
        int p = tid >> 3, corner = tid & 7;
        int i = corner >> 2, j = (corner >> 1) & 1, k = corner & 1;
        float wx = i ? ptT[2][p] : 1.0f - ptT[2][p];
        float wy = j ? ptT[1][p] : 1.0f - ptT[1][p];
        float wz = k ? ptT[0][p] : 1.0f - ptT[0][p];
        wcorn[p][corner] = wx * wy * wz;
    }

    // gather h (coalesced bf16 cvT) into wave-private Xin; 2 threads per batch row
    {
        const int r = tid >> 1, h = tid & 1;
        const int p = r >> 3, corner = r & 7;
        const int i0 = corner >> 2, i1 = (corner >> 1) & 1, i2 = corner & 1;
        int cell = (ptCI[0][p] + i0) * 1024 + (ptCI[1][p] + i1) * 32 + ptCI[2][p] + i2;
        const uint4* src = (const uint4*)&cvT[cell * 96];
        uint4* dstX = (uint4*)&Xin[r * SA];
        #pragma unroll
        for (int cc = h * 6; cc < h * 6 + 6; ++cc) dstX[cc] = src[cc];
    }

    // coord-feature B-fragments (kc=3,4 of layer-0) computed straight into
    // registers in MFMA B-layout: lane l16 = row col0+nt*16+l16, elem (quad,j)
    // covers feature index f = (kc-3)*32 + quad*8 + j. Each sin/cos of the
    // block is computed exactly once (quad-partitioned), no LDS staging.
    short8 bF3[2], bF4[2];
    #pragma unroll
    for (int nt = 0; nt < 2; ++nt) {
        const int r = col0 + nt * 16 + l16;
        const int p = r >> 3, corner = r & 7;
        const int io[3] = {corner >> 2, (corner >> 1) & 1, corner & 1};
        float rn[3], cc3[3], qp[3];
        #pragma unroll
        for (int c = 0; c < 3; ++c) {
            float rel = fmaxf(ptBase[c][p] + (float)io[c] * vox[c], lim[c]);
            rn[c] = (rel - mrel[c][io[c]]) * inv3v[c];
            cc3[c] = org[c] + (float)(ptCI[c][p] + io[c]) * vox[c];
            qp[c] = ptQ[c][p];
        }
        float fa[8], fb[8];
        if (quad == 0) {
            fa[0] = qv[0]; fa[1] = qv[1]; fa[2] = qv[2];
            fa[3] = cc3[0]; fa[4] = cc3[1]; fa[5] = cc3[2];
            fa[6] = qp[0]; fa[7] = qp[1];
            #pragma unroll
            for (int m = 0; m < 4; ++m) fb[m]     = sin_r(rn[1] * FREQH[4 + m]);
            #pragma unroll
            for (int m = 0; m < 4; ++m) fb[4 + m] = cos_r(rn[1] * FREQH[m]);
        } else if (quad == 1) {
            fa[0] = qp[2]; fa[1] = rn[0]; fa[2] = rn[1]; fa[3] = rn[2];
            #pragma unroll
            for (int m = 0; m < 4; ++m) fa[4 + m] = sin_r(rn[0] * FREQH[m]);
            #pragma unroll
            for (int m = 0; m < 4; ++m) fb[m]     = cos_r(rn[1] * FREQH[4 + m]);
            #pragma unroll
            for (int m = 0; m < 4; ++m) fb[4 + m] = sin_r(rn[2] * FREQH[m]);
        } else if (quad == 2) {
            #pragma unroll
            for (int m = 0; m < 4; ++m) fa[m]     = sin_r(rn[0] * FREQH[4 + m]);
            #pragma unroll
            for (int m = 0; m < 4; ++m) fa[4 + m] = cos_r(rn[0] * FREQH[m]);
            #pragma unroll
            for (int m = 0; m < 4; ++m) fb[m]     = sin_r(rn[2] * FREQH[4 + m]);
            #pragma unroll
            for (int m = 0; m < 4; ++m) fb[4 + m] = cos_r(rn[2] * FREQH[m]);
        } else {
            #pragma unroll
            for (int m = 0; m < 4; ++m) fa[m]     = cos_r(rn[0] * FREQH[4 + m]);
            #pragma unroll
            for (int m = 0; m < 4; ++m) fa[4 + m] = sin_r(rn[1] * FREQH[m]);
            #pragma unroll
            for (int m = 0; m < 4; ++m) fb[m]     = cos_r(rn[2] * FREQH[4 + m]);
            fb[4] = 0.f; fb[5] = 0.f; fb[6] = 0.f; fb[7] = 0.f;   // k=156..159 (weights also zeroed)
        }
        bF3[nt] = pk8(fa);
        bF4[nt] = pk8(fb);
    }
    __syncthreads();

    const int A32off[2] = {L0A, L0B};
    const int A16off[2][2] = {{A1_00, A1_01}, {A1_10, A1_11}};
    // Fused-epilogue MLP, nt-inner: per-mt accumulators are transient; the
    // two nt chains interleave for ILP. Persistent: bA/bB fragments.
    shrt4 bA[6][2], bB[6][2];

    #pragma unroll
    for (int blk = 0; blk < 2; ++blk) {
        // ---- layer 0: K=160, mfma 16x16x32; bias rides in as C; silu fused -> bA
        {
            short8 bX[2][3];
            #pragma unroll
            for (int nt = 0; nt < 2; ++nt)
                #pragma unroll
                for (int kc = 0; kc < 3; ++kc)
                    bX[nt][kc] = *(const short8*)&Xin[(col0 + nt * 16 + l16) * SA + kc * 32 + quad8];
            const int lay = blk * 3;
            #pragma unroll
            for (int mt = 0; mt < 6; ++mt) {
                short8 aw[5];
                #pragma unroll
                for (int kc = 0; kc < 5; ++kc)
                    aw[kc] = *(const short8*)&wsW[A32off[blk] + ((mt * 5 + kc) << 9) + lane8];
                floatx4 bv = *(const floatx4*)&biasF[((lay * 6 + mt) << 8) + (lane << 2)];
                #pragma unroll
                for (int nt = 0; nt < 2; ++nt) {
                    floatx4 a = __builtin_amdgcn_mfma_f32_16x16x32_bf16(aw[0], bX[nt][0], bv, 0, 0, 0);
                    a = __builtin_amdgcn_mfma_f32_16x16x32_bf16(aw[1], bX[nt][1], a, 0, 0, 0);
                    a = __builtin_amdgcn_mfma_f32_16x16x32_bf16(aw[2], bX[nt][2], a, 0, 0, 0);
                    a = __builtin_amdgcn_mfma_f32_16x16x32_bf16(aw[3], bF3[nt], a, 0, 0, 0);
                    a = __builtin_amdgcn_mfma_f32_16x16x32_bf16(aw[4], bF4[nt], a, 0, 0, 0);
                    bA[mt][nt] = pk4(silu4(a));
                }
            }
        }
        // ---- layer 1: K=96, mfma 16x16x16 chained from bA; silu fused -> bB
        {
            const int lay = blk * 3 + 1;
            #pragma unroll
            for (int mt = 0; mt < 6; ++mt) {
                short8 awp[3];
                #pragma unroll
                for (int kp = 0; kp < 3; ++kp)
                    awp[kp] = *(const short8*)&wsW[A16off[blk][0] + ((mt * 3 + kp) << 9) + lane8];
                floatx4 bv = *(const floatx4*)&biasF[((lay * 6 + mt) << 8) + (lane << 2)];
                #pragma unroll
                for (int nt = 0; nt < 2; ++nt) {
                    shrt4 a0 = __builtin_shufflevector(awp[0], awp[0], 0, 1, 2, 3);
                    floatx4 a = MFMA16(a0, bA[0][nt], bv);
                    #pragma unroll
                    for (int kc = 1; kc < 6; ++kc) {
                        shrt4 af = (kc & 1)
                            ? __builtin_shufflevector(awp[kc >> 1], awp[kc >> 1], 4, 5, 6, 7)
                            : __builtin_shufflevector(awp[kc >> 1], awp[kc >> 1], 0, 1, 2, 3);
                        a = MFMA16(af, bA[kc][nt], a);
                    }
                    bB[mt][nt] = pk4(silu4(a));
                }
            }
        }
        // ---- layer 2: K=96 from bB; silu + residual + h write-back fused (wave-private Xin)
        {
            const int lay = blk * 3 + 2;
            #pragma unroll
            for (int mt = 0; mt < 6; ++mt) {
                short8 awp[3];
                #pragma unroll
                for (int kp = 0; kp < 3; ++kp)
                    awp[kp] = *(const short8*)&wsW[A16off[blk][1] + ((mt * 3 + kp) << 9) + lane8];
                floatx4 bv = *(const floatx4*)&biasF[((lay * 6 + mt) << 8) + (lane << 2)];
                #pragma unroll
                for (int nt = 0; nt < 2; ++nt) {
                    shrt4 a0 = __builtin_shufflevector(awp[0], awp[0], 0, 1, 2, 3);
                    floatx4 a = MFMA16(a0, bB[0][nt], bv);
                    #pragma unroll
                    for (int kc = 1; kc < 6; ++kc) {
                        shrt4 af = (kc & 1)
                            ? __builtin_shufflevector(awp[kc >> 1], awp[kc >> 1], 4, 5, 6, 7)
                            : __builtin_shufflevector(awp[kc >> 1], awp[kc >> 1], 0, 1, 2, 3);
                        a = MFMA16(af, bB[kc][nt], a);
                    }
                    int ca = (col0 + nt * 16 + l16) * SA + mt * 16 + quad4;
                    ush4 hu = *(const ush4*)&Xin[ca];      // residual source
                    floatx4 s;
                    #pragma unroll
                    for (int r = 0; r < 4; ++r)
                        s[r] = a[r] * __builtin_amdgcn_rcpf(1.0f + __expf(-a[r])) + bf2f(hu[r]);
                    uintx2 w;
                    w[0] = pkpair(s[0], s[1]);
                    w[1] = pkpair(s[2], s[3]);
                    *(uintx2*)&Xin[ca] = w;                // same-wave readers only
                }
            }
        }
    }

    // blend 8 corners -> Hhat (wave-private), b32 reads + hi/lo unpack
    {
        int p = tid >> 4, s6 = (tid & 15) * 6;
        float w8[8];
        #pragma unroll
        for (int c = 0; c < 8; ++c) w8[c] = wcorn[p][c];
        float sum[6] = {0.f, 0.f, 0.f, 0.f, 0.f, 0.f};
        #pragma unroll
        for (int c = 0; c < 8; ++c) {
            const unsigned* rp = (const unsigned*)&Xin[(p * 8 + c) * SA + s6];
            float w = w8[c];
            #pragma unroll
            for (int d = 0; d < 3; ++d) {
                unsigned u = rp[d];
                sum[d * 2]     += w * __uint_as_float(u << 16);
                sum[d * 2 + 1] += w * __uint_as_float(u & 0xFFFF0000u);
            }
        }
        unsigned* hp = (unsigned*)&Hhat[p * SW + s6];
        #pragma unroll
        for (int d = 0; d < 3; ++d) hp[d] = pkpair(sum[d * 2], sum[d * 2 + 1]);
    }
    __syncthreads();   // Hhat is read cross-wave by the post GEMM

    // post GEMM: 16 points x 48(45) out channels
    if (wv < 3) {
        const ushort_t* wb = wsW + PST;
        floatx4 pacc = {0.f, 0.f, 0.f, 0.f};
        #pragma unroll
        for (int kc = 0; kc < 3; ++kc) {
            short8 a = *(const short8*)&Hhat[l16 * SW + kc * 32 + quad8];
            short8 bfrag = *(const short8*)&wb[((wv * 3 + kc) << 9) + lane8];
            pacc = __builtin_amdgcn_mfma_f32_16x16x32_bf16(a, bfrag, pacc, 0, 0, 0);
        }
        int n = 16 * wv + l16;
        if (n < 45) {
            float bv = pb[n];
            float4 v;
            v.x = pacc[0] + bv; v.y = pacc[1] + bv; v.z = pacc[2] + bv; v.w = pacc[3] + bv;
            *(float4*)&out[n * NQ + p0 + quad * 4] = v;
        }
    }
}

extern "C" void kernel_launch(void* const* d_in, const int* in_sizes, int n_in,
                              void* d_out, int out_size, void* d_ws, size_t ws_size,
                              hipStream_t stream) {
    (void)in_sizes; (void)n_in; (void)out_size; (void)ws_size;
    const float* cv  = (const float*)d_in[0];
    const float* ext = (const float*)d_in[1];
    const float* qvx = (const float*)d_in[2];
    const float* qc  = (const float*)d_in[3];
    const float* w00 = (const float*)d_in[4];
    const float* b00 = (const float*)d_in[5];
    const float* w01 = (const float*)d_in[6];
    const float* b01 = (const float*)d_in[7];
    const float* w02 = (const float*)d_in[8];
    const float* b02 = (const float*)d_in[9];
    const float* w10 = (const float*)d_in[10];
    const float* b10 = (const float*)d_in[11];
    const float* w11 = (const float*)d_in[12];
    const float* b11 = (const float*)d_in[13];
    const float* w12 = (const float*)d_in[14];
    const float* b12 = (const float*)d_in[15];
    const float* pw  = (const float*)d_in[16];
    const float* pb  = (const float*)d_in[17];

    unsigned* keys = (unsigned*)d_ws;
    ushort_t* wsW  = (ushort_t*)((char*)d_ws + WSW_OFF);
    float* biasF   = (float*)((char*)d_ws + BIAS_OFF);
    ushort_t* cvT  = (ushort_t*)((char*)d_ws + CVT_OFF);

    hipMemsetAsync(keys, 0xFF, 12, stream);   // atomicMin identity (graph-safe)
    decoder_pre<<<PRE_NB, 256, 0, stream>>>(cv, cvT,
                                            w00, b00, w01, b01, w02, b02,
                                            w10, b10, w11, b11, w12, b12,
                                            pw, wsW, biasF, qc, ext, keys);
    decoder_main<<<6912, 256, 0, stream>>>(cvT, ext, qvx, qc,
                                           pb, wsW, biasF, keys, (float*)d_out);
}

// Round 6
// 318.984 us; speedup vs baseline: 1.2110x; 1.0102x over previous
//
#include <hip/hip_runtime.h>
#include <hip/hip_bf16.h>

typedef unsigned short ushort_t;
typedef short short8 __attribute__((ext_vector_type(8)));
typedef short shrt4 __attribute__((ext_vector_type(4)));
typedef unsigned short ush4 __attribute__((ext_vector_type(4)));
typedef unsigned int uintx2 __attribute__((ext_vector_type(2)));
typedef unsigned int uintx4 __attribute__((ext_vector_type(4)));
typedef float floatx4 __attribute__((ext_vector_type(4)));

#define SA 104   // Xin row stride in bf16 elems (h only): 208B = 13*16, 52 dwords % 32 = 20 (conflict-free class)
#define SW 104   // Hhat stride
#define NQ 110592
#define CVOL 32768

// wsW bf16 element offsets
#define L0A   0        // blk0 l0 weights, 16x16x32 A-layout [mt6][kc5][lane][8]
#define L0B   15360    // blk1 l0
#define A1_00 30720    // blk0 l1 weights, 16x16x16 A-layout [mt6][kp3][lane][kl2*4+i]
#define A1_01 39936    // blk0 l2
#define A1_10 49152    // blk1 l1
#define A1_11 58368    // blk1 l2
#define PST   67584    // post weights, 16x16x32 B-layout
#define WTOT  72192
#define BTOT  9216     // bias floats, C-layout [layer6][mt6][lane][r4]

// ws byte offsets
#define WSW_OFF  64
#define BIAS_OFF 147456
#define KEYS_OFF 184320   // 432*4 u32 per-block min slots (fits the 12 KB gap before CVT_OFF)
#define CVT_OFF  196608

// merged pre-kernel block ranges
#define TXP_NB   512     // 2x blocks vs r5 (64 cols each): TXP was 1 block/CU latency-bound
#define PREP_NB  318
#define MINP_NB  432
#define PRE_NB   (TXP_NB + PREP_NB + MINP_NB)

#if defined(__HIP_DEVICE_COMPILE__)
#define MFMA16(A, B, C) __builtin_amdgcn_mfma_f32_16x16x16bf16_1k(A, B, C, 0, 0, 0)
#else
#define MFMA16(A, B, C) (C)
#endif

#if defined(__HIP_DEVICE_COMPILE__) && __has_builtin(__builtin_amdgcn_sinf) && __has_builtin(__builtin_amdgcn_cosf) && __has_builtin(__builtin_amdgcn_fractf)
#define FAST_SINCOS 1
#else
#define FAST_SINCOS 0
#endif

__device__ __forceinline__ float bf2f(ushort_t u) { return __uint_as_float(((unsigned)u) << 16); }
__device__ __forceinline__ ushort_t f2bf(float f) {         // exact RNE (cold paths)
    unsigned u = __float_as_uint(f);
    unsigned r = (u + 0x7fffu + ((u >> 16) & 1u)) >> 16;
    return (ushort_t)r;
}
// hot-path pack: two f32 -> packed bf16 pair. cvt_pk if HW has it, else
// round-half-up (+0x8000) + v_perm (1.5 ops/elem; differs from RNE only on exact ties).
__device__ __forceinline__ unsigned pkpair(float a, float b) {
#if defined(__HIP_DEVICE_COMPILE__) && __has_builtin(__builtin_amdgcn_cvt_pk_bf16_f32)
    return __builtin_bit_cast(unsigned, __builtin_amdgcn_cvt_pk_bf16_f32(a, b));
#else
    unsigned ua = __float_as_uint(a) + 0x8000u;
    unsigned ub = __float_as_uint(b) + 0x8000u;
    return __builtin_amdgcn_perm(ub, ua, 0x07060302);   // lo16=hi(ua), hi16=hi(ub)
#endif
}
__device__ __forceinline__ shrt4 pk4(floatx4 v) {
    uintx2 u;
    u[0] = pkpair(v[0], v[1]);
    u[1] = pkpair(v[2], v[3]);
    return __builtin_bit_cast(shrt4, u);
}
__device__ __forceinline__ short8 pk8(const float (&v)[8]) {
    uintx4 u;
    u[0] = pkpair(v[0], v[1]);
    u[1] = pkpair(v[2], v[3]);
    u[2] = pkpair(v[4], v[5]);
    u[3] = pkpair(v[6], v[7]);
    return __builtin_bit_cast(short8, u);
}
__device__ __forceinline__ floatx4 silu4(floatx4 z) {
    floatx4 s;
    #pragma unroll
    for (int r = 0; r < 4; ++r)
        s[r] = z[r] * __builtin_amdgcn_rcpf(1.0f + __expf(-z[r]));
    return s;
}
__device__ __forceinline__ unsigned encodeMin(float x) {
    unsigned u = __float_as_uint(x);
    return (u & 0x80000000u) ? ~u : (u | 0x80000000u);
}
__device__ __forceinline__ float decodeMin(unsigned key) {
    unsigned u = (key & 0x80000000u) ? (key ^ 0x80000000u) : ~key;
    return __uint_as_float(u);
}

// revolutions-domain sin/cos (matches reference sin(2*pi*ang))
__device__ __forceinline__ float sin_r(float ang) {
#if FAST_SINCOS
    return __builtin_amdgcn_sinf(__builtin_amdgcn_fractf(ang));
#else
    float s, c; sincospif(2.0f * ang, &s, &c); return s;
#endif
}
__device__ __forceinline__ float cos_r(float ang) {
#if FAST_SINCOS
    return __builtin_amdgcn_cosf(__builtin_amdgcn_fractf(ang));
#else
    float s, c; sincospif(2.0f * ang, &s, &c); return c;
#endif
}

__device__ __constant__ float FREQ[8] = {
    1.0f, 1.2228445f, 1.4953488f, 1.8285791f,
    2.2360680f, 2.7343640f, 3.3437015f, 4.0888269f
};
// compile-time-foldable copy for fully unrolled fragment assembly
constexpr float FREQH[8] = {
    1.0f, 1.2228445f, 1.4953488f, 1.8285791f,
    2.2360680f, 2.7343640f, 3.3437015f, 4.0888269f
};

// ---------------- merged pre-kernel: txp | weight/bias swizzle | min-prepass ----------------
// No memset dependency: prepass writes per-block mins to fixed keysArr slots
// (all 432*3 slots written unconditionally); decoder_main reduces them.
__global__ void decoder_pre(const float* __restrict__ cv, ushort_t* __restrict__ cvT,
                            const float* __restrict__ w00, const float* __restrict__ b00,
                            const float* __restrict__ w01, const float* __restrict__ b01,
                            const float* __restrict__ w02, const float* __restrict__ b02,
                            const float* __restrict__ w10, const float* __restrict__ b10,
                            const float* __restrict__ w11, const float* __restrict__ b11,
                            const float* __restrict__ w12, const float* __restrict__ b12,
                            const float* __restrict__ pw, ushort_t* __restrict__ wsW,
                            float* __restrict__ biasF,
                            const float* __restrict__ qc, const float* __restrict__ ext,
                            unsigned* __restrict__ keysArr) {
    __shared__ ushort_t ld[64 * SW];
    __shared__ unsigned mk[3];
    const int bx = blockIdx.x;
    const int tid = threadIdx.x;

    if (bx < TXP_NB) {            // ---- transpose cv [96][32768] fp32 -> cvT [32768][96] bf16
        int base = bx * 64;       // 64 columns per block (2x parallelism vs r5)
        int cl = tid & 63, h = tid >> 6;          // h in 0..3, 24 channels each
        #pragma unroll 4
        for (int ch = h * 24; ch < h * 24 + 24; ++ch)
            ld[cl * SW + ch] = f2bf(cv[ch * CVOL + base + cl]);
        __syncthreads();
        #pragma unroll
        for (int it = 0; it < 3; ++it) {          // 64 rows x 12 uint4 = 768
            int idx = it * 256 + tid;
            int r = idx / 12, c = idx - r * 12;
            *(uint4*)&cvT[(base + r) * 96 + c * 8] = *(const uint4*)&ld[r * SW + c * 8];
        }
        return;
    }
    if (bx < TXP_NB + PREP_NB) {  // ---- weight swizzle + bias C-layout
        int idx = (bx - TXP_NB) * 256 + tid;
        if (idx >= WTOT + BTOT) return;
        if (idx >= WTOT) {
            int t = idx - WTOT;
            int layer = t / 1536, rem = t - layer * 1536;
            int mt = rem >> 8, l2i = rem & 255;
            int lane = l2i >> 2, r = l2i & 3;
            int m = mt * 16 + (lane >> 4) * 4 + r;
            const float* B = layer == 0 ? b00 : layer == 1 ? b01 : layer == 2 ? b02
                           : layer == 3 ? b10 : layer == 4 ? b11 : b12;
            biasF[t] = B[m];
            return;
        }
        ushort_t v = 0;
        if (idx < A1_00) {            // layer-0 weights: 16x16x32 A-layout
            const float* W = (idx < L0B) ? w00 : w10;
            int li = idx - ((idx < L0B) ? L0A : L0B);
            int j = li & 7, lane = (li >> 3) & 63, chunk = li >> 9;
            int kc = chunk % 5, mt = chunk / 5;
            int k = kc * 32 + (lane >> 4) * 8 + j;
            int m = mt * 16 + (lane & 15);
            if (k < 156) v = f2bf(W[k * 96 + m]);
        } else if (idx < PST) {       // layer-1/2 weights: 16x16x16 A-layout
            const float* W = idx < A1_01 ? w01 : idx < A1_10 ? w02 : idx < A1_11 ? w11 : w12;
            int off = idx < A1_01 ? A1_00 : idx < A1_10 ? A1_01 : idx < A1_11 ? A1_10 : A1_11;
            int li = idx - off;
            int i = li & 3, kl = (li >> 2) & 1, lane = (li >> 3) & 63, chunk = li >> 9;
            int kp = chunk % 3, mt = chunk / 3;
            int k = (kp * 2 + kl) * 16 + (lane >> 4) * 4 + i;
            int m = mt * 16 + (lane & 15);
            v = f2bf(W[k * 96 + m]);
        } else {                      // post weights: 16x16x32 B-layout
            int li = idx - PST;
            int j = li & 7, lane = (li >> 3) & 63, chunk = li >> 9;
            int kc = chunk % 3, t = chunk / 3;
            int k = kc * 32 + (lane >> 4) * 8 + j;
            int n = t * 16 + (lane & 15);
            if (n < 45) v = f2bf(pw[k * 45 + n]);
        }
        wsW[idx] = v;
        return;
    }
    // ---- prepass: per-block min of base_c = org + ci*vox - q -> keysArr[pb][c]
    {
        int lane = tid & 63;
        if (tid < 3) mk[tid] = 0xFFFFFFFFu;
        __syncthreads();
        int pb = bx - TXP_NB - PREP_NB;
        int p = pb * 256 + tid;
        #pragma unroll
        for (int c = 0; c < 3; ++c) {
            float org = ext[c * CVOL];
            float vox = fabsf(ext[c * CVOL + 1057] - org);
            float q = qc[c * NQ + p];
            float nf = rintf((q - org) / vox);
            int ci = (int)nf; ci = ci < 0 ? 0 : (ci > 30 ? 30 : ci);
            float base = org + (float)ci * vox - q;
            for (int off = 32; off > 0; off >>= 1) base = fminf(base, __shfl_xor(base, off));
            if (lane == 0) atomicMin(&mk[c], encodeMin(base));
        }
        __syncthreads();
        if (tid < 3) keysArr[pb * 4 + tid] = mk[tid];   // plain store, no init needed
    }
}

// ---------------- main fused kernel ----------------
// Structure = round-3 best (nt-INNER MLP; ILP across the two nt chains hides
// MFMA+silu latency — round 4's nt-outer lost 36%). (256,3) is the verified
// no-scratch attribute config; allocator settles at 64 arch VGPRs + AGPR block
// (~150 total -> 3 waves/SIMD). New here: waves 1-3 reduce the 432 per-block
// min slots (replaces the memset+atomicMin global dependency chain).
__global__ __launch_bounds__(256, 3) void decoder_main(
    const ushort_t* __restrict__ cvT, const float* __restrict__ ext,
    const float* __restrict__ qvx, const float* __restrict__ qc,
    const float* __restrict__ pb, const ushort_t* __restrict__ wsW,
    const float* __restrict__ biasF,
    const unsigned* __restrict__ keysArr, float* __restrict__ out)
{
    __shared__ ushort_t Xin[128 * SA];     // rows = batch (point,corner), cols = h(96) + 8 pad
    __shared__ ushort_t Hhat[16 * SW];
    __shared__ float ptQ[3][16], ptBase[3][16], ptT[3][16];
    __shared__ int ptCI[3][16];
    __shared__ float wcorn[16][8];
    __shared__ unsigned mkS[4];

    const int tid = threadIdx.x;
    const int lane = tid & 63;
    const int wv = tid >> 6;
    const int quad = lane >> 4;
    const int l16 = lane & 15;
    const int lane8 = lane << 3, quad8 = quad * 8, quad4 = quad * 4;
    const int p0 = blockIdx.x * 16;
    const int col0 = wv * 32;              // wave-private batch columns [col0, col0+32)

    // broadcast scalars
    float vox[3], org[3], lim[3], inv3v[3], qv[3];
    #pragma unroll
    for (int c = 0; c < 3; ++c) {
        org[c] = ext[c * CVOL];
        vox[c] = fabsf(ext[c * CVOL + 1057] - org[c]);
        lim[c] = -0.5f * vox[c] + 1e-7f;
        inv3v[c] = 1.0f / (1.5f * vox[c]);
        qv[c] = qvx[c];
    }

    // per-point setup (wave 0)
    if (tid < 64) {
        int p = tid >> 2, c = tid & 3;
        if (c < 3) {
            float q = qc[c * NQ + p0 + p];
            float nf = rintf((q - org[c]) / vox[c]);   // RNE == jnp.round
            int ci = (int)nf; ci = ci < 0 ? 0 : (ci > 30 ? 30 : ci);
            float base = org[c] + (float)ci * vox[c] - q;
            float rel0 = fmaxf(base, lim[c]);
            float g = fminf(fmaxf((rel0 - 0.5f) * 2.0f, -1.0f + 1e-7f), 1.0f - 1e-7f);
            ptQ[c][p] = q; ptCI[c][p] = ci; ptBase[c][p] = base; ptT[c][p] = (g + 1.0f) * 0.5f;
        }
    } else {
        // waves 1-3: reduce the 432 per-block min keys for channel wv-1
        // (encoded domain is min-order-preserving). Hidden before barrier 1.
        int c = wv - 1;
        unsigned m = 0xFFFFFFFFu;
        #pragma unroll
        for (int i = 0; i < 7; ++i) {
            int idx = i * 64 + lane;
            if (idx < MINP_NB) m = min(m, keysArr[idx * 4 + c]);
        }
        #pragma unroll
        for (int off = 32; off > 0; off >>= 1)
            m = min(m, (unsigned)__shfl_xor((int)m, off));
        if (lane == 0) mkS[c] = m;
    }
    __syncthreads();

    // global-min-derived rel normalizers (was: decodeMin(minKeys[c]))
    float mrel[3][2];
    #pragma unroll
    for (int c = 0; c < 3; ++c) {
        float mb = decodeMin(mkS[c]);
        mrel[c][0] = fmaxf(mb, lim[c]);
        mrel[c][1] = fmaxf(mb + vox[c], lim[c]);
    }

    // trilinear corner weights (reference's channel swap: i->t[2], j->t[1], k->t[0])
    if (tid < 128) {
        int p = tid >> 3, corner = tid & 7;
        int i = corner >> 2, j = (corner >> 1) & 1, k = corner & 1;
        float wx = i ? ptT[2][p] : 1.0f - ptT[2][p];
        float wy = j ? ptT[1][p] : 1.0f - ptT[1][p];
        float wz = k ? ptT[0][p] : 1.0f - ptT[0][p];
        wcorn[p][corner] = wx * wy * wz;
    }

    // gather h (coalesced bf16 cvT) into wave-private Xin; 2 threads per batch row
    {
        const int r = tid >> 1, h = tid & 1;
        const int p = r >> 3, corner = r & 7;
        const int i0 = corner >> 2, i1 = (corner >> 1) & 1, i2 = corner & 1;
        int cell = (ptCI[0][p] + i0) * 1024 + (ptCI[1][p] + i1) * 32 + ptCI[2][p] + i2;
        const uint4* src = (const uint4*)&cvT[cell * 96];
        uint4* dstX = (uint4*)&Xin[r * SA];
        #pragma unroll
        for (int cc = h * 6; cc < h * 6 + 6; ++cc) dstX[cc] = src[cc];
    }

    // coord-feature B-fragments (kc=3,4 of layer-0) computed straight into
    // registers in MFMA B-layout: lane l16 = row col0+nt*16+l16, elem (quad,j)
    // covers feature index f = (kc-3)*32 + quad*8 + j. Each sin/cos of the
    // block is computed exactly once (quad-partitioned), no LDS staging.
    short8 bF3[2], bF4[2];
    #pragma unroll
    for (int nt = 0; nt < 2; ++nt) {
        const int r = col0 + nt * 16 + l16;
        const int p = r >> 3, corner = r & 7;
        const int io[3] = {corner >> 2, (corner >> 1) & 1, corner & 1};
        float rn[3], cc3[3], qp[3];
        #pragma unroll
        for (int c = 0; c < 3; ++c) {
            float rel = fmaxf(ptBase[c][p] + (float)io[c] * vox[c], lim[c]);
            rn[c] = (rel - mrel[c][io[c]]) * inv3v[c];
            cc3[c] = org[c] + (float)(ptCI[c][p] + io[c]) * vox[c];
            qp[c] = ptQ[c][p];
        }
        float fa[8], fb[8];
        if (quad == 0) {
            fa[0] = qv[0]; fa[1] = qv[1]; fa[2] = qv[2];
            fa[3] = cc3[0]; fa[4] = cc3[1]; fa[5] = cc3[2];
            fa[6] = qp[0]; fa[7] = qp[1];
            #pragma unroll
            for (int m = 0; m < 4; ++m) fb[m]     = sin_r(rn[1] * FREQH[4 + m]);
            #pragma unroll
            for (int m = 0; m < 4; ++m) fb[4 + m] = cos_r(rn[1] * FREQH[m]);
        } else if (quad == 1) {
            fa[0] = qp[2]; fa[1] = rn[0]; fa[2] = rn[1]; fa[3] = rn[2];
            #pragma unroll
            for (int m = 0; m < 4; ++m) fa[4 + m] = sin_r(rn[0] * FREQH[m]);
            #pragma unroll
            for (int m = 0; m < 4; ++m) fb[m]     = cos_r(rn[1] * FREQH[4 + m]);
            #pragma unroll
            for (int m = 0; m < 4; ++m) fb[4 + m] = sin_r(rn[2] * FREQH[m]);
        } else if (quad == 2) {
            #pragma unroll
            for (int m = 0; m < 4; ++m) fa[m]     = sin_r(rn[0] * FREQH[4 + m]);
            #pragma unroll
            for (int m = 0; m < 4; ++m) fa[4 + m] = cos_r(rn[0] * FREQH[m]);
            #pragma unroll
            for (int m = 0; m < 4; ++m) fb[m]     = sin_r(rn[2] * FREQH[4 + m]);
            #pragma unroll
            for (int m = 0; m < 4; ++m) fb[4 + m] = cos_r(rn[2] * FREQH[m]);
        } else {
            #pragma unroll
            for (int m = 0; m < 4; ++m) fa[m]     = cos_r(rn[0] * FREQH[4 + m]);
            #pragma unroll
            for (int m = 0; m < 4; ++m) fa[4 + m] = sin_r(rn[1] * FREQH[m]);
            #pragma unroll
            for (int m = 0; m < 4; ++m) fb[m]     = cos_r(rn[2] * FREQH[4 + m]);
            fb[4] = 0.f; fb[5] = 0.f; fb[6] = 0.f; fb[7] = 0.f;   // k=156..159 (weights also zeroed)
        }
        bF3[nt] = pk8(fa);
        bF4[nt] = pk8(fb);
    }
    __syncthreads();

    const int A32off[2] = {L0A, L0B};
    const int A16off[2][2] = {{A1_00, A1_01}, {A1_10, A1_11}};
    // Fused-epilogue MLP, nt-inner: per-mt accumulators are transient; the
    // two nt chains interleave for ILP. Persistent: bA/bB fragments.
    shrt4 bA[6][2], bB[6][2];

    #pragma unroll
    for (int blk = 0; blk < 2; ++blk) {
        // ---- layer 0: K=160, mfma 16x16x32; bias rides in as C; silu fused -> bA
        {
            short8 bX[2][3];
            #pragma unroll
            for (int nt = 0; nt < 2; ++nt)
                #pragma unroll
                for (int kc = 0; kc < 3; ++kc)
                    bX[nt][kc] = *(const short8*)&Xin[(col0 + nt * 16 + l16) * SA + kc * 32 + quad8];
            const int lay = blk * 3;
            #pragma unroll
            for (int mt = 0; mt < 6; ++mt) {
                short8 aw[5];
                #pragma unroll
                for (int kc = 0; kc < 5; ++kc)
                    aw[kc] = *(const short8*)&wsW[A32off[blk] + ((mt * 5 + kc) << 9) + lane8];
                floatx4 bv = *(const floatx4*)&biasF[((lay * 6 + mt) << 8) + (lane << 2)];
                #pragma unroll
                for (int nt = 0; nt < 2; ++nt) {
                    floatx4 a = __builtin_amdgcn_mfma_f32_16x16x32_bf16(aw[0], bX[nt][0], bv, 0, 0, 0);
                    a = __builtin_amdgcn_mfma_f32_16x16x32_bf16(aw[1], bX[nt][1], a, 0, 0, 0);
                    a = __builtin_amdgcn_mfma_f32_16x16x32_bf16(aw[2], bX[nt][2], a, 0, 0, 0);
                    a = __builtin_amdgcn_mfma_f32_16x16x32_bf16(aw[3], bF3[nt], a, 0, 0, 0);
                    a = __builtin_amdgcn_mfma_f32_16x16x32_bf16(aw[4], bF4[nt], a, 0, 0, 0);
                    bA[mt][nt] = pk4(silu4(a));
                }
            }
        }
        // ---- layer 1: K=96, mfma 16x16x16 chained from bA; silu fused -> bB
        {
            const int lay = blk * 3 + 1;
            #pragma unroll
            for (int mt = 0; mt < 6; ++mt) {
                short8 awp[3];
                #pragma unroll
                for (int kp = 0; kp < 3; ++kp)
                    awp[kp] = *(const short8*)&wsW[A16off[blk][0] + ((mt * 3 + kp) << 9) + lane8];
                floatx4 bv = *(const floatx4*)&biasF[((lay * 6 + mt) << 8) + (lane << 2)];
                #pragma unroll
                for (int nt = 0; nt < 2; ++nt) {
                    shrt4 a0 = __builtin_shufflevector(awp[0], awp[0], 0, 1, 2, 3);
                    floatx4 a = MFMA16(a0, bA[0][nt], bv);
                    #pragma unroll
                    for (int kc = 1; kc < 6; ++kc) {
                        shrt4 af = (kc & 1)
                            ? __builtin_shufflevector(awp[kc >> 1], awp[kc >> 1], 4, 5, 6, 7)
                            : __builtin_shufflevector(awp[kc >> 1], awp[kc >> 1], 0, 1, 2, 3);
                        a = MFMA16(af, bA[kc][nt], a);
                    }
                    bB[mt][nt] = pk4(silu4(a));
                }
            }
        }
        // ---- layer 2: K=96 from bB; silu + residual + h write-back fused (wave-private Xin)
        {
            const int lay = blk * 3 + 2;
            #pragma unroll
            for (int mt = 0; mt < 6; ++mt) {
                short8 awp[3];
                #pragma unroll
                for (int kp = 0; kp < 3; ++kp)
                    awp[kp] = *(const short8*)&wsW[A16off[blk][1] + ((mt * 3 + kp) << 9) + lane8];
                floatx4 bv = *(const floatx4*)&biasF[((lay * 6 + mt) << 8) + (lane << 2)];
                #pragma unroll
                for (int nt = 0; nt < 2; ++nt) {
                    shrt4 a0 = __builtin_shufflevector(awp[0], awp[0], 0, 1, 2, 3);
                    floatx4 a = MFMA16(a0, bB[0][nt], bv);
                    #pragma unroll
                    for (int kc = 1; kc < 6; ++kc) {
                        shrt4 af = (kc & 1)
                            ? __builtin_shufflevector(awp[kc >> 1], awp[kc >> 1], 4, 5, 6, 7)
                            : __builtin_shufflevector(awp[kc >> 1], awp[kc >> 1], 0, 1, 2, 3);
                        a = MFMA16(af, bB[kc][nt], a);
                    }
                    int ca = (col0 + nt * 16 + l16) * SA + mt * 16 + quad4;
                    ush4 hu = *(const ush4*)&Xin[ca];      // residual source
                    floatx4 s;
                    #pragma unroll
                    for (int r = 0; r < 4; ++r)
                        s[r] = a[r] * __builtin_amdgcn_rcpf(1.0f + __expf(-a[r])) + bf2f(hu[r]);
                    uintx2 w;
                    w[0] = pkpair(s[0], s[1]);
                    w[1] = pkpair(s[2], s[3]);
                    *(uintx2*)&Xin[ca] = w;                // same-wave readers only
                }
            }
        }
    }

    // blend 8 corners -> Hhat (wave-private), b32 reads + hi/lo unpack
    {
        int p = tid >> 4, s6 = (tid & 15) * 6;
        float w8[8];
        #pragma unroll
        for (int c = 0; c < 8; ++c) w8[c] = wcorn[p][c];
        float sum[6] = {0.f, 0.f, 0.f, 0.f, 0.f, 0.f};
        #pragma unroll
        for (int c = 0; c < 8; ++c) {
            const unsigned* rp = (const unsigned*)&Xin[(p * 8 + c) * SA + s6];
            float w = w8[c];
            #pragma unroll
            for (int d = 0; d < 3; ++d) {
                unsigned u = rp[d];
                sum[d * 2]     += w * __uint_as_float(u << 16);
                sum[d * 2 + 1] += w * __uint_as_float(u & 0xFFFF0000u);
            }
        }
        unsigned* hp = (unsigned*)&Hhat[p * SW + s6];
        #pragma unroll
        for (int d = 0; d < 3; ++d) hp[d] = pkpair(sum[d * 2], sum[d * 2 + 1]);
    }
    __syncthreads();   // Hhat is read cross-wave by the post GEMM

    // post GEMM: 16 points x 48(45) out channels
    if (wv < 3) {
        const ushort_t* wb = wsW + PST;
        floatx4 pacc = {0.f, 0.f, 0.f, 0.f};
        #pragma unroll
        for (int kc = 0; kc < 3; ++kc) {
            short8 a = *(const short8*)&Hhat[l16 * SW + kc * 32 + quad8];
            short8 bfrag = *(const short8*)&wb[((wv * 3 + kc) << 9) + lane8];
            pacc = __builtin_amdgcn_mfma_f32_16x16x32_bf16(a, bfrag, pacc, 0, 0, 0);
        }
        int n = 16 * wv + l16;
        if (n < 45) {
            float bv = pb[n];
            float4 v;
            v.x = pacc[0] + bv; v.y = pacc[1] + bv; v.z = pacc[2] + bv; v.w = pacc[3] + bv;
            *(float4*)&out[n * NQ + p0 + quad * 4] = v;
        }
    }
}

extern "C" void kernel_launch(void* const* d_in, const int* in_sizes, int n_in,
                              void* d_out, int out_size, void* d_ws, size_t ws_size,
                              hipStream_t stream) {
    (void)in_sizes; (void)n_in; (void)out_size; (void)ws_size;
    const float* cv  = (const float*)d_in[0];
    const float* ext = (const float*)d_in[1];
    const float* qvx = (const float*)d_in[2];
    const float* qc  = (const float*)d_in[3];
    const float* w00 = (const float*)d_in[4];
    const float* b00 = (const float*)d_in[5];
    const float* w01 = (const float*)d_in[6];
    const float* b01 = (const float*)d_in[7];
    const float* w02 = (const float*)d_in[8];
    const float* b02 = (const float*)d_in[9];
    const float* w10 = (const float*)d_in[10];
    const float* b10 = (const float*)d_in[11];
    const float* w11 = (const float*)d_in[12];
    const float* b11 = (const float*)d_in[13];
    const float* w12 = (const float*)d_in[14];
    const float* b12 = (const float*)d_in[15];
    const float* pw  = (const float*)d_in[16];
    const float* pb  = (const float*)d_in[17];

    ushort_t* wsW  = (ushort_t*)((char*)d_ws + WSW_OFF);
    float* biasF   = (float*)((char*)d_ws + BIAS_OFF);
    unsigned* keys = (unsigned*)((char*)d_ws + KEYS_OFF);
    ushort_t* cvT  = (ushort_t*)((char*)d_ws + CVT_OFF);

    decoder_pre<<<PRE_NB, 256, 0, stream>>>(cv, cvT,
                                            w00, b00, w01, b01, w02, b02,
                                            w10, b10, w11, b11, w12, b12,
                                            pw, wsW, biasF, qc, ext, keys);
    decoder_main<<<6912, 256, 0, stream>>>(cvT, ext, qvx, qc,
                                           pb, wsW, biasF, keys, (float*)d_out);
}

// Round 7
// 310.241 us; speedup vs baseline: 1.2451x; 1.0282x over previous
//
#include <hip/hip_runtime.h>
#include <hip/hip_bf16.h>

typedef unsigned short ushort_t;
typedef short short8 __attribute__((ext_vector_type(8)));
typedef short shrt4 __attribute__((ext_vector_type(4)));
typedef unsigned short ush4 __attribute__((ext_vector_type(4)));
typedef unsigned int uintx2 __attribute__((ext_vector_type(2)));
typedef unsigned int uintx4 __attribute__((ext_vector_type(4)));
typedef float floatx4 __attribute__((ext_vector_type(4)));

#define SA 104   // Xin row stride in bf16 elems (h only): 208B = 13*16, 52 dwords % 32 = 20 (conflict-free class)
#define SW 104   // Hhat stride
#define NQ 110592
#define CVOL 32768

// wsW bf16 element offsets
#define L0A   0        // blk0 l0 weights, 16x16x32 A-layout [mt6][kc5][lane][8]
#define L0B   15360    // blk1 l0
#define A1_00 30720    // blk0 l1 weights, 16x16x16 A-layout [mt6][kp3][lane][kl2*4+i]
#define A1_01 39936    // blk0 l2
#define A1_10 49152    // blk1 l1
#define A1_11 58368    // blk1 l2
#define PST   67584    // post weights, 16x16x32 B-layout
#define WTOT  72192
#define BTOT  9216     // bias floats, C-layout [layer6][mt6][lane][r4]

// ws byte offsets
#define WSW_OFF  64
#define BIAS_OFF 147456
#define KEYS_OFF 184320   // 432*4 u32 per-block min slots (fits the 12 KB gap before CVT_OFF)
#define CVT_OFF  196608

// merged pre-kernel block ranges
#define TXP_NB   512     // 64 cols/block
#define PREP_NB  318
#define MINP_NB  432
#define PRE_NB   (TXP_NB + PREP_NB + MINP_NB)

#if defined(__HIP_DEVICE_COMPILE__)
#define MFMA16(A, B, C) __builtin_amdgcn_mfma_f32_16x16x16bf16_1k(A, B, C, 0, 0, 0)
#else
#define MFMA16(A, B, C) (C)
#endif

#if defined(__HIP_DEVICE_COMPILE__) && __has_builtin(__builtin_amdgcn_sinf) && __has_builtin(__builtin_amdgcn_cosf) && __has_builtin(__builtin_amdgcn_fractf)
#define FAST_SINCOS 1
#else
#define FAST_SINCOS 0
#endif

__device__ __forceinline__ float bf2f(ushort_t u) { return __uint_as_float(((unsigned)u) << 16); }
__device__ __forceinline__ ushort_t f2bf(float f) {         // exact RNE (cold paths)
    unsigned u = __float_as_uint(f);
    unsigned r = (u + 0x7fffu + ((u >> 16) & 1u)) >> 16;
    return (ushort_t)r;
}
// hot-path pack: two f32 -> packed bf16 pair. cvt_pk if HW has it, else
// round-half-up (+0x8000) + v_perm (1.5 ops/elem; differs from RNE only on exact ties).
__device__ __forceinline__ unsigned pkpair(float a, float b) {
#if defined(__HIP_DEVICE_COMPILE__) && __has_builtin(__builtin_amdgcn_cvt_pk_bf16_f32)
    return __builtin_bit_cast(unsigned, __builtin_amdgcn_cvt_pk_bf16_f32(a, b));
#else
    unsigned ua = __float_as_uint(a) + 0x8000u;
    unsigned ub = __float_as_uint(b) + 0x8000u;
    return __builtin_amdgcn_perm(ub, ua, 0x07060302);   // lo16=hi(ua), hi16=hi(ub)
#endif
}
__device__ __forceinline__ shrt4 pk4(floatx4 v) {
    uintx2 u;
    u[0] = pkpair(v[0], v[1]);
    u[1] = pkpair(v[2], v[3]);
    return __builtin_bit_cast(shrt4, u);
}
__device__ __forceinline__ short8 pk8(const float (&v)[8]) {
    uintx4 u;
    u[0] = pkpair(v[0], v[1]);
    u[1] = pkpair(v[2], v[3]);
    u[2] = pkpair(v[4], v[5]);
    u[3] = pkpair(v[6], v[7]);
    return __builtin_bit_cast(short8, u);
}
__device__ __forceinline__ floatx4 silu4(floatx4 z) {
    floatx4 s;
    #pragma unroll
    for (int r = 0; r < 4; ++r)
        s[r] = z[r] * __builtin_amdgcn_rcpf(1.0f + __expf(-z[r]));
    return s;
}
__device__ __forceinline__ unsigned encodeMin(float x) {
    unsigned u = __float_as_uint(x);
    return (u & 0x80000000u) ? ~u : (u | 0x80000000u);
}
__device__ __forceinline__ float decodeMin(unsigned key) {
    unsigned u = (key & 0x80000000u) ? (key ^ 0x80000000u) : ~key;
    return __uint_as_float(u);
}

// revolutions-domain sin/cos (matches reference sin(2*pi*ang))
__device__ __forceinline__ float sin_r(float ang) {
#if FAST_SINCOS
    return __builtin_amdgcn_sinf(__builtin_amdgcn_fractf(ang));
#else
    float s, c; sincospif(2.0f * ang, &s, &c); return s;
#endif
}
__device__ __forceinline__ float cos_r(float ang) {
#if FAST_SINCOS
    return __builtin_amdgcn_cosf(__builtin_amdgcn_fractf(ang));
#else
    float s, c; sincospif(2.0f * ang, &s, &c); return c;
#endif
}

__device__ __constant__ float FREQ[8] = {
    1.0f, 1.2228445f, 1.4953488f, 1.8285791f,
    2.2360680f, 2.7343640f, 3.3437015f, 4.0888269f
};
// compile-time-foldable copy for fully unrolled fragment assembly
constexpr float FREQH[8] = {
    1.0f, 1.2228445f, 1.4953488f, 1.8285791f,
    2.2360680f, 2.7343640f, 3.3437015f, 4.0888269f
};

// ---------------- merged pre-kernel: txp | weight/bias swizzle | min-prepass ----------------
// No memset dependency: prepass writes per-block mins to fixed keysArr slots
// (all 432*3 slots written unconditionally); decoder_main reduces them.
__global__ void decoder_pre(const float* __restrict__ cv, ushort_t* __restrict__ cvT,
                            const float* __restrict__ w00, const float* __restrict__ b00,
                            const float* __restrict__ w01, const float* __restrict__ b01,
                            const float* __restrict__ w02, const float* __restrict__ b02,
                            const float* __restrict__ w10, const float* __restrict__ b10,
                            const float* __restrict__ w11, const float* __restrict__ b11,
                            const float* __restrict__ w12, const float* __restrict__ b12,
                            const float* __restrict__ pw, ushort_t* __restrict__ wsW,
                            float* __restrict__ biasF,
                            const float* __restrict__ qc, const float* __restrict__ ext,
                            unsigned* __restrict__ keysArr) {
    __shared__ ushort_t ld[64 * SW];
    __shared__ unsigned mk[3];
    const int bx = blockIdx.x;
    const int tid = threadIdx.x;

    if (bx < TXP_NB) {            // ---- transpose cv [96][32768] fp32 -> cvT [32768][96] bf16
        int base = bx * 64;       // 64 columns per block
        int cl = tid & 63, h = tid >> 6;          // h in 0..3, 24 channels each
        #pragma unroll 4
        for (int ch = h * 24; ch < h * 24 + 24; ++ch)
            ld[cl * SW + ch] = f2bf(cv[ch * CVOL + base + cl]);
        __syncthreads();
        #pragma unroll
        for (int it = 0; it < 3; ++it) {          // 64 rows x 12 uint4 = 768
            int idx = it * 256 + tid;
            int r = idx / 12, c = idx - r * 12;
            *(uint4*)&cvT[(base + r) * 96 + c * 8] = *(const uint4*)&ld[r * SW + c * 8];
        }
        return;
    }
    if (bx < TXP_NB + PREP_NB) {  // ---- weight swizzle + bias C-layout
        int idx = (bx - TXP_NB) * 256 + tid;
        if (idx >= WTOT + BTOT) return;
        if (idx >= WTOT) {
            int t = idx - WTOT;
            int layer = t / 1536, rem = t - layer * 1536;
            int mt = rem >> 8, l2i = rem & 255;
            int lane = l2i >> 2, r = l2i & 3;
            int m = mt * 16 + (lane >> 4) * 4 + r;
            const float* B = layer == 0 ? b00 : layer == 1 ? b01 : layer == 2 ? b02
                           : layer == 3 ? b10 : layer == 4 ? b11 : b12;
            biasF[t] = B[m];
            return;
        }
        ushort_t v = 0;
        if (idx < A1_00) {            // layer-0 weights: 16x16x32 A-layout
            const float* W = (idx < L0B) ? w00 : w10;
            int li = idx - ((idx < L0B) ? L0A : L0B);
            int j = li & 7, lane = (li >> 3) & 63, chunk = li >> 9;
            int kc = chunk % 5, mt = chunk / 5;
            int k = kc * 32 + (lane >> 4) * 8 + j;
            int m = mt * 16 + (lane & 15);
            if (k < 156) v = f2bf(W[k * 96 + m]);
        } else if (idx < PST) {       // layer-1/2 weights: 16x16x16 A-layout
            const float* W = idx < A1_01 ? w01 : idx < A1_10 ? w02 : idx < A1_11 ? w11 : w12;
            int off = idx < A1_01 ? A1_00 : idx < A1_10 ? A1_01 : idx < A1_11 ? A1_10 : A1_11;
            int li = idx - off;
            int i = li & 3, kl = (li >> 2) & 1, lane = (li >> 3) & 63, chunk = li >> 9;
            int kp = chunk % 3, mt = chunk / 3;
            int k = (kp * 2 + kl) * 16 + (lane >> 4) * 4 + i;
            int m = mt * 16 + (lane & 15);
            v = f2bf(W[k * 96 + m]);
        } else {                      // post weights: 16x16x32 B-layout
            int li = idx - PST;
            int j = li & 7, lane = (li >> 3) & 63, chunk = li >> 9;
            int kc = chunk % 3, t = chunk / 3;
            int k = kc * 32 + (lane >> 4) * 8 + j;
            int n = t * 16 + (lane & 15);
            if (n < 45) v = f2bf(pw[k * 45 + n]);
        }
        wsW[idx] = v;
        return;
    }
    // ---- prepass: per-block min of base_c = org + ci*vox - q -> keysArr[pb][c]
    {
        int lane = tid & 63;
        if (tid < 3) mk[tid] = 0xFFFFFFFFu;
        __syncthreads();
        int pb = bx - TXP_NB - PREP_NB;
        int p = pb * 256 + tid;
        #pragma unroll
        for (int c = 0; c < 3; ++c) {
            float org = ext[c * CVOL];
            float vox = fabsf(ext[c * CVOL + 1057] - org);
            float q = qc[c * NQ + p];
            float nf = rintf((q - org) / vox);
            int ci = (int)nf; ci = ci < 0 ? 0 : (ci > 30 ? 30 : ci);
            float base = org + (float)ci * vox - q;
            for (int off = 32; off > 0; off >>= 1) base = fminf(base, __shfl_xor(base, off));
            if (lane == 0) atomicMin(&mk[c], encodeMin(base));
        }
        __syncthreads();
        if (tid < 3) keysArr[pb * 4 + tid] = mk[tid];   // plain store, no init needed
    }
}

// ---------------- main fused kernel ----------------
// Structure = round-3 best (nt-INNER MLP; ILP across the two nt chains hides
// MFMA+silu latency — nt-outer lost 36% to latency). (256,3) is the verified
// no-scratch attribute config; allocator settles at ~150 total regs/wave
// (64 arch VGPR + AGPR block) -> 3.4 waves/SIMD against the 512-reg file,
// which is exactly the measured 42% occupancy. R6->R7 change: barrier #2
// removed — everything between barrier #1 and the Hhat barrier is wave-
// private (gather rows, features, MLP, blend all stay in each wave's 32
// columns); the only cross-wave data it protected (wcorn) is now computed
// per-thread from ptT in the blend (~20 VALU once, -512B LDS).
__global__ __launch_bounds__(256, 3) void decoder_main(
    const ushort_t* __restrict__ cvT, const float* __restrict__ ext,
    const float* __restrict__ qvx, const float* __restrict__ qc,
    const float* __restrict__ pb, const ushort_t* __restrict__ wsW,
    const float* __restrict__ biasF,
    const unsigned* __restrict__ keysArr, float* __restrict__ out)
{
    __shared__ ushort_t Xin[128 * SA];     // rows = batch (point,corner), cols = h(96) + 8 pad
    __shared__ ushort_t Hhat[16 * SW];
    __shared__ float ptQ[3][16], ptBase[3][16], ptT[3][16];
    __shared__ int ptCI[3][16];
    __shared__ unsigned mkS[4];

    const int tid = threadIdx.x;
    const int lane = tid & 63;
    const int wv = tid >> 6;
    const int quad = lane >> 4;
    const int l16 = lane & 15;
    const int lane8 = lane << 3, quad8 = quad * 8, quad4 = quad * 4;
    const int p0 = blockIdx.x * 16;
    const int col0 = wv * 32;              // wave-private batch columns [col0, col0+32)

    // broadcast scalars
    float vox[3], org[3], lim[3], inv3v[3], qv[3];
    #pragma unroll
    for (int c = 0; c < 3; ++c) {
        org[c] = ext[c * CVOL];
        vox[c] = fabsf(ext[c * CVOL + 1057] - org[c]);
        lim[c] = -0.5f * vox[c] + 1e-7f;
        inv3v[c] = 1.0f / (1.5f * vox[c]);
        qv[c] = qvx[c];
    }

    // per-point setup (wave 0)
    if (tid < 64) {
        int p = tid >> 2, c = tid & 3;
        if (c < 3) {
            float q = qc[c * NQ + p0 + p];
            float nf = rintf((q - org[c]) / vox[c]);   // RNE == jnp.round
            int ci = (int)nf; ci = ci < 0 ? 0 : (ci > 30 ? 30 : ci);
            float base = org[c] + (float)ci * vox[c] - q;
            float rel0 = fmaxf(base, lim[c]);
            float g = fminf(fmaxf((rel0 - 0.5f) * 2.0f, -1.0f + 1e-7f), 1.0f - 1e-7f);
            ptQ[c][p] = q; ptCI[c][p] = ci; ptBase[c][p] = base; ptT[c][p] = (g + 1.0f) * 0.5f;
        }
    } else {
        // waves 1-3: reduce the 432 per-block min keys for channel wv-1
        // (encoded domain is min-order-preserving). Hidden before barrier 1.
        int c = wv - 1;
        unsigned m = 0xFFFFFFFFu;
        #pragma unroll
        for (int i = 0; i < 7; ++i) {
            int idx = i * 64 + lane;
            if (idx < MINP_NB) m = min(m, keysArr[idx * 4 + c]);
        }
        #pragma unroll
        for (int off = 32; off > 0; off >>= 1)
            m = min(m, (unsigned)__shfl_xor((int)m, off));
        if (lane == 0) mkS[c] = m;
    }
    __syncthreads();   // barrier #1: ptQ/ptCI/ptBase/ptT + mkS visible to all waves

    // global-min-derived rel normalizers
    float mrel[3][2];
    #pragma unroll
    for (int c = 0; c < 3; ++c) {
        float mb = decodeMin(mkS[c]);
        mrel[c][0] = fmaxf(mb, lim[c]);
        mrel[c][1] = fmaxf(mb + vox[c], lim[c]);
    }

    // gather h (coalesced bf16 cvT) into wave-private Xin; 2 threads per batch row
    // (rows tid>>1 are wave-private: wave w writes exactly rows 32w..32w+31)
    {
        const int r = tid >> 1, h = tid & 1;
        const int p = r >> 3, corner = r & 7;
        const int i0 = corner >> 2, i1 = (corner >> 1) & 1, i2 = corner & 1;
        int cell = (ptCI[0][p] + i0) * 1024 + (ptCI[1][p] + i1) * 32 + ptCI[2][p] + i2;
        const uint4* src = (const uint4*)&cvT[cell * 96];
        uint4* dstX = (uint4*)&Xin[r * SA];
        #pragma unroll
        for (int cc = h * 6; cc < h * 6 + 6; ++cc) dstX[cc] = src[cc];
    }

    // coord-feature B-fragments (kc=3,4 of layer-0) computed straight into
    // registers in MFMA B-layout: lane l16 = row col0+nt*16+l16, elem (quad,j)
    // covers feature index f = (kc-3)*32 + quad*8 + j. Each sin/cos of the
    // block is computed exactly once (quad-partitioned), no LDS staging.
    short8 bF3[2], bF4[2];
    #pragma unroll
    for (int nt = 0; nt < 2; ++nt) {
        const int r = col0 + nt * 16 + l16;
        const int p = r >> 3, corner = r & 7;
        const int io[3] = {corner >> 2, (corner >> 1) & 1, corner & 1};
        float rn[3], cc3[3], qp[3];
        #pragma unroll
        for (int c = 0; c < 3; ++c) {
            float rel = fmaxf(ptBase[c][p] + (float)io[c] * vox[c], lim[c]);
            rn[c] = (rel - mrel[c][io[c]]) * inv3v[c];
            cc3[c] = org[c] + (float)(ptCI[c][p] + io[c]) * vox[c];
            qp[c] = ptQ[c][p];
        }
        float fa[8], fb[8];
        if (quad == 0) {
            fa[0] = qv[0]; fa[1] = qv[1]; fa[2] = qv[2];
            fa[3] = cc3[0]; fa[4] = cc3[1]; fa[5] = cc3[2];
            fa[6] = qp[0]; fa[7] = qp[1];
            #pragma unroll
            for (int m = 0; m < 4; ++m) fb[m]     = sin_r(rn[1] * FREQH[4 + m]);
            #pragma unroll
            for (int m = 0; m < 4; ++m) fb[4 + m] = cos_r(rn[1] * FREQH[m]);
        } else if (quad == 1) {
            fa[0] = qp[2]; fa[1] = rn[0]; fa[2] = rn[1]; fa[3] = rn[2];
            #pragma unroll
            for (int m = 0; m < 4; ++m) fa[4 + m] = sin_r(rn[0] * FREQH[m]);
            #pragma unroll
            for (int m = 0; m < 4; ++m) fb[m]     = cos_r(rn[1] * FREQH[4 + m]);
            #pragma unroll
            for (int m = 0; m < 4; ++m) fb[4 + m] = sin_r(rn[2] * FREQH[m]);
        } else if (quad == 2) {
            #pragma unroll
            for (int m = 0; m < 4; ++m) fa[m]     = sin_r(rn[0] * FREQH[4 + m]);
            #pragma unroll
            for (int m = 0; m < 4; ++m) fa[4 + m] = cos_r(rn[0] * FREQH[m]);
            #pragma unroll
            for (int m = 0; m < 4; ++m) fb[m]     = sin_r(rn[2] * FREQH[4 + m]);
            #pragma unroll
            for (int m = 0; m < 4; ++m) fb[4 + m] = cos_r(rn[2] * FREQH[m]);
        } else {
            #pragma unroll
            for (int m = 0; m < 4; ++m) fa[m]     = cos_r(rn[0] * FREQH[4 + m]);
            #pragma unroll
            for (int m = 0; m < 4; ++m) fa[4 + m] = sin_r(rn[1] * FREQH[m]);
            #pragma unroll
            for (int m = 0; m < 4; ++m) fb[m]     = cos_r(rn[2] * FREQH[4 + m]);
            fb[4] = 0.f; fb[5] = 0.f; fb[6] = 0.f; fb[7] = 0.f;   // k=156..159 (weights also zeroed)
        }
        bF3[nt] = pk8(fa);
        bF4[nt] = pk8(fb);
    }
    // NO barrier here: Xin gather rows, features, the whole MLP, and the blend
    // are wave-private (each wave touches only its own 32 Xin rows). The old
    // barrier #2 protected only wcorn, now computed per-thread in the blend.

    const int A32off[2] = {L0A, L0B};
    const int A16off[2][2] = {{A1_00, A1_01}, {A1_10, A1_11}};
    // Fused-epilogue MLP, nt-inner: per-mt accumulators are transient; the
    // two nt chains interleave for ILP. Persistent: bA/bB fragments.
    shrt4 bA[6][2], bB[6][2];

    #pragma unroll
    for (int blk = 0; blk < 2; ++blk) {
        // ---- layer 0: K=160, mfma 16x16x32; bias rides in as C; silu fused -> bA
        {
            short8 bX[2][3];
            #pragma unroll
            for (int nt = 0; nt < 2; ++nt)
                #pragma unroll
                for (int kc = 0; kc < 3; ++kc)
                    bX[nt][kc] = *(const short8*)&Xin[(col0 + nt * 16 + l16) * SA + kc * 32 + quad8];
            const int lay = blk * 3;
            #pragma unroll
            for (int mt = 0; mt < 6; ++mt) {
                short8 aw[5];
                #pragma unroll
                for (int kc = 0; kc < 5; ++kc)
                    aw[kc] = *(const short8*)&wsW[A32off[blk] + ((mt * 5 + kc) << 9) + lane8];
                floatx4 bv = *(const floatx4*)&biasF[((lay * 6 + mt) << 8) + (lane << 2)];
                #pragma unroll
                for (int nt = 0; nt < 2; ++nt) {
                    floatx4 a = __builtin_amdgcn_mfma_f32_16x16x32_bf16(aw[0], bX[nt][0], bv, 0, 0, 0);
                    a = __builtin_amdgcn_mfma_f32_16x16x32_bf16(aw[1], bX[nt][1], a, 0, 0, 0);
                    a = __builtin_amdgcn_mfma_f32_16x16x32_bf16(aw[2], bX[nt][2], a, 0, 0, 0);
                    a = __builtin_amdgcn_mfma_f32_16x16x32_bf16(aw[3], bF3[nt], a, 0, 0, 0);
                    a = __builtin_amdgcn_mfma_f32_16x16x32_bf16(aw[4], bF4[nt], a, 0, 0, 0);
                    bA[mt][nt] = pk4(silu4(a));
                }
            }
        }
        // ---- layer 1: K=96, mfma 16x16x16 chained from bA; silu fused -> bB
        {
            const int lay = blk * 3 + 1;
            #pragma unroll
            for (int mt = 0; mt < 6; ++mt) {
                short8 awp[3];
                #pragma unroll
                for (int kp = 0; kp < 3; ++kp)
                    awp[kp] = *(const short8*)&wsW[A16off[blk][0] + ((mt * 3 + kp) << 9) + lane8];
                floatx4 bv = *(const floatx4*)&biasF[((lay * 6 + mt) << 8) + (lane << 2)];
                #pragma unroll
                for (int nt = 0; nt < 2; ++nt) {
                    shrt4 a0 = __builtin_shufflevector(awp[0], awp[0], 0, 1, 2, 3);
                    floatx4 a = MFMA16(a0, bA[0][nt], bv);
                    #pragma unroll
                    for (int kc = 1; kc < 6; ++kc) {
                        shrt4 af = (kc & 1)
                            ? __builtin_shufflevector(awp[kc >> 1], awp[kc >> 1], 4, 5, 6, 7)
                            : __builtin_shufflevector(awp[kc >> 1], awp[kc >> 1], 0, 1, 2, 3);
                        a = MFMA16(af, bA[kc][nt], a);
                    }
                    bB[mt][nt] = pk4(silu4(a));
                }
            }
        }
        // ---- layer 2: K=96 from bB; silu + residual + h write-back fused (wave-private Xin)
        {
            const int lay = blk * 3 + 2;
            #pragma unroll
            for (int mt = 0; mt < 6; ++mt) {
                short8 awp[3];
                #pragma unroll
                for (int kp = 0; kp < 3; ++kp)
                    awp[kp] = *(const short8*)&wsW[A16off[blk][1] + ((mt * 3 + kp) << 9) + lane8];
                floatx4 bv = *(const floatx4*)&biasF[((lay * 6 + mt) << 8) + (lane << 2)];
                #pragma unroll
                for (int nt = 0; nt < 2; ++nt) {
                    shrt4 a0 = __builtin_shufflevector(awp[0], awp[0], 0, 1, 2, 3);
                    floatx4 a = MFMA16(a0, bB[0][nt], bv);
                    #pragma unroll
                    for (int kc = 1; kc < 6; ++kc) {
                        shrt4 af = (kc & 1)
                            ? __builtin_shufflevector(awp[kc >> 1], awp[kc >> 1], 4, 5, 6, 7)
                            : __builtin_shufflevector(awp[kc >> 1], awp[kc >> 1], 0, 1, 2, 3);
                        a = MFMA16(af, bB[kc][nt], a);
                    }
                    int ca = (col0 + nt * 16 + l16) * SA + mt * 16 + quad4;
                    ush4 hu = *(const ush4*)&Xin[ca];      // residual source
                    floatx4 s;
                    #pragma unroll
                    for (int r = 0; r < 4; ++r)
                        s[r] = a[r] * __builtin_amdgcn_rcpf(1.0f + __expf(-a[r])) + bf2f(hu[r]);
                    uintx2 w;
                    w[0] = pkpair(s[0], s[1]);
                    w[1] = pkpair(s[2], s[3]);
                    *(uintx2*)&Xin[ca] = w;                // same-wave readers only
                }
            }
        }
    }

    // blend 8 corners -> Hhat (wave-private rows), corner weights computed
    // per-thread from ptT (replaces the wcorn LDS array + its barrier).
    {
        int p = tid >> 4, s6 = (tid & 15) * 6;
        float t2 = ptT[2][p], t1 = ptT[1][p], t0 = ptT[0][p];
        float w8[8];
        #pragma unroll
        for (int c = 0; c < 8; ++c) {
            float wx = (c & 4) ? t2 : 1.0f - t2;
            float wy = (c & 2) ? t1 : 1.0f - t1;
            float wz = (c & 1) ? t0 : 1.0f - t0;
            w8[c] = wx * wy * wz;
        }
        float sum[6] = {0.f, 0.f, 0.f, 0.f, 0.f, 0.f};
        #pragma unroll
        for (int c = 0; c < 8; ++c) {
            const unsigned* rp = (const unsigned*)&Xin[(p * 8 + c) * SA + s6];
            float w = w8[c];
            #pragma unroll
            for (int d = 0; d < 3; ++d) {
                unsigned u = rp[d];
                sum[d * 2]     += w * __uint_as_float(u << 16);
                sum[d * 2 + 1] += w * __uint_as_float(u & 0xFFFF0000u);
            }
        }
        unsigned* hp = (unsigned*)&Hhat[p * SW + s6];
        #pragma unroll
        for (int d = 0; d < 3; ++d) hp[d] = pkpair(sum[d * 2], sum[d * 2 + 1]);
    }
    __syncthreads();   // Hhat is read cross-wave by the post GEMM

    // post GEMM: 16 points x 48(45) out channels
    if (wv < 3) {
        const ushort_t* wb = wsW + PST;
        floatx4 pacc = {0.f, 0.f, 0.f, 0.f};
        #pragma unroll
        for (int kc = 0; kc < 3; ++kc) {
            short8 a = *(const short8*)&Hhat[l16 * SW + kc * 32 + quad8];
            short8 bfrag = *(const short8*)&wb[((wv * 3 + kc) << 9) + lane8];
            pacc = __builtin_amdgcn_mfma_f32_16x16x32_bf16(a, bfrag, pacc, 0, 0, 0);
        }
        int n = 16 * wv + l16;
        if (n < 45) {
            float bv = pb[n];
            float4 v;
            v.x = pacc[0] + bv; v.y = pacc[1] + bv; v.z = pacc[2] + bv; v.w = pacc[3] + bv;
            *(float4*)&out[n * NQ + p0 + quad * 4] = v;
        }
    }
}

extern "C" void kernel_launch(void* const* d_in, const int* in_sizes, int n_in,
                              void* d_out, int out_size, void* d_ws, size_t ws_size,
                              hipStream_t stream) {
    (void)in_sizes; (void)n_in; (void)out_size; (void)ws_size;
    const float* cv  = (const float*)d_in[0];
    const float* ext = (const float*)d_in[1];
    const float* qvx = (const float*)d_in[2];
    const float* qc  = (const float*)d_in[3];
    const float* w00 = (const float*)d_in[4];
    const float* b00 = (const float*)d_in[5];
    const float* w01 = (const float*)d_in[6];
    const float* b01 = (const float*)d_in[7];
    const float* w02 = (const float*)d_in[8];
    const float* b02 = (const float*)d_in[9];
    const float* w10 = (const float*)d_in[10];
    const float* b10 = (const float*)d_in[11];
    const float* w11 = (const float*)d_in[12];
    const float* b11 = (const float*)d_in[13];
    const float* w12 = (const float*)d_in[14];
    const float* b12 = (const float*)d_in[15];
    const float* pw  = (const float*)d_in[16];
    const float* pb  = (const float*)d_in[17];

    ushort_t* wsW  = (ushort_t*)((char*)d_ws + WSW_OFF);
    float* biasF   = (float*)((char*)d_ws + BIAS_OFF);
    unsigned* keys = (unsigned*)((char*)d_ws + KEYS_OFF);
    ushort_t* cvT  = (ushort_t*)((char*)d_ws + CVT_OFF);

    decoder_pre<<<PRE_NB, 256, 0, stream>>>(cv, cvT,
                                            w00, b00, w01, b01, w02, b02,
                                            w10, b10, w11, b11, w12, b12,
                                            pw, wsW, biasF, qc, ext, keys);
    decoder_main<<<6912, 256, 0, stream>>>(cvT, ext, qvx, qc,
                                           pb, wsW, biasF, keys, (float*)d_out);
}